// Round 3
// baseline (8381.722 us; speedup 1.0000x reference)
//
#include <hip/hip_runtime.h>
#include <stdint.h>

typedef __attribute__((ext_vector_type(8))) short short8;
typedef __attribute__((ext_vector_type(4))) float f32x4;

#define NT 15

// packed bf16 weight fragments in d_ws (element offsets, shorts)
#define SET0 0          // L0: 32 (jt,g) pairs x 5 kt x 512
#define SET1 81920      // L1: 32 pairs x 8 kt x 512
#define SET2 212992     // dec: same shape as L1
#define SET3 344064     // heads [Wm;Ws]: 4 kt x 512
#define PK_TOTAL 346112
#define DBASE_OFF (PK_TOTAL*2)   // byte offset of dbase in ws

__device__ __forceinline__ unsigned short f2bf(float f){
  unsigned int u = __builtin_bit_cast(unsigned int, f);
  u += 0x7fffu + ((u >> 16) & 1u);
  return (unsigned short)(u >> 16);
}
__device__ __forceinline__ float sigf(float x){
  return __builtin_amdgcn_rcpf(1.0f + __expf(-x));
}
__device__ __forceinline__ float tanhf_(float x){
  return 1.0f - 2.0f*__builtin_amdgcn_rcpf(1.0f + __expf(2.0f*x));
}
// XOR-swizzled LDS index (shorts): spreads stride-256B rows across banks.
__device__ __forceinline__ int sidx(int row, int col){
  return row*128 + (col ^ ((row & 7) << 3));
}

// ---------------- prep: pack weights to bf16 MFMA fragments ----------------
__global__ void pack_w(const float* __restrict__ Wih0, const float* __restrict__ Whh0,
                       const float* __restrict__ Wih1, const float* __restrict__ Whh1,
                       const float* __restrict__ Wihd, const float* __restrict__ Whhd,
                       const float* __restrict__ Wm,  const float* __restrict__ Ws,
                       unsigned short* __restrict__ pk)
{
  int idx = blockIdx.x*256 + threadIdx.x;
  if (idx >= PK_TOTAL) return;
  float v = 0.f;
  if (idx >= SET3){
    int e = idx - SET3;
    int j = e & 7, lane = (e >> 3) & 63, kt = e >> 9;
    int n = lane & 15;
    int k = kt*32 + (lane >> 4)*8 + j;
    if (n < 3) v = Wm[n*128 + k];
    else if (n < 6) v = Ws[(n-3)*128 + k];
  } else {
    int set, e;
    if (idx < SET1){ set = 0; e = idx; }
    else if (idx < SET2){ set = 1; e = idx - SET1; }
    else { set = 2; e = idx - SET2; }
    int j = e & 7, lane = (e >> 3) & 63, rest = e >> 9;
    int nf = (set == 0) ? 5 : 8;
    int kt = rest % nf, pair = rest / nf;
    int g = pair & 3, jt = pair >> 2;
    int n = g*128 + jt*16 + (lane & 15);
    int kk = (lane >> 4)*8 + j;
    if (set == 0){
      if (kt < 4) v = Whh0[n*128 + kt*32 + kk];
      else if (kk < 6) v = Wih0[n*6 + kk];
    } else {
      const float* Wi = (set == 1) ? Wih1 : Wihd;
      const float* Wh = (set == 1) ? Whh1 : Whhd;
      v = (kt < 4) ? Wi[n*128 + kt*32 + kk] : Wh[n*128 + (kt-4)*32 + kk];
    }
  }
  pk[idx] = f2bf(v);
}

__global__ void prep_decbase(const float* __restrict__ emb, const float* __restrict__ Wp,
                             const float* __restrict__ bp, float* __restrict__ dbase)
{
  int idx = blockIdx.x*128 + threadIdx.x;
  if (idx >= 1280) return;
  int s = idx >> 7, j = idx & 127;
  float acc = bp[j];
  for (int k = 0; k < 128; ++k) acc += emb[s*128 + k] * Wp[j*131 + 3 + k];
  dbase[idx] = acc;
}

union DecShared {
  unsigned short xs[8*64*8];                  // 8192 B: x chunk [tt][row][8]
  struct {
    float sred[8][64][2];                     // LN partials per wave
    float mus[64][2];                         // mu, rstd per row
    float prevb[64][4];                       // prev-mu broadcast
  } d;
};

// ---------------- main fused kernel ----------------
// 512 thr = 8 waves; block owns 64 rows; wave w owns h-columns [w*16,w*16+16)
// across all 4 gates. Single-buffered LDS (in-place h update with pre-read
// of hazard fragments) -> 40960 B LDS -> 3-4 blocks/CU.
__global__ __launch_bounds__(512, 6)
void traj_main(const float* __restrict__ x,
               const unsigned short* __restrict__ pk,
               const float* __restrict__ dbase,
               const float* __restrict__ b0g, const float* __restrict__ b1g,
               const float* __restrict__ bdg,
               const float* __restrict__ Wp,
               const float* __restrict__ bm, const float* __restrict__ bs,
               const float* __restrict__ lng, const float* __restrict__ lnb,
               float* __restrict__ out)
{
  __shared__ __align__(16) unsigned short hA[64*128];
  __shared__ __align__(16) unsigned short hB[64*128];
  __shared__ __align__(16) DecShared u;

  const int tid  = threadIdx.x;
  const int w    = tid >> 6;
  const int lane = tid & 63;
  const int lidx = lane & 15;
  const int lgrp = lane >> 4;
  const int col  = w*16 + lidx;
  const int row0 = blockIdx.x * 64;

  for (int i = tid; i < 64*128; i += 512){ hA[i] = 0; hB[i] = 0; }
  // stage x chunk 0 (t = 0..7)
  for (int i = tid; i < 8*64*8; i += 512){
    int k8 = i & 7, r = (i >> 3) & 63, tt = i >> 9;
    u.xs[i] = (k8 < 6) ? f2bf(x[(size_t)(row0 + r)*90 + tt*6 + k8]) : (unsigned short)0;
  }

  float b0v[4], b1v[4];
  #pragma unroll
  for (int g = 0; g < 4; ++g){ b0v[g] = b0g[g*128 + col]; b1v[g] = b1g[g*128 + col]; }

  float c0s[4][4], c1s[4][4];
  #pragma unroll
  for (int m = 0; m < 4; ++m)
    #pragma unroll
    for (int r = 0; r < 4; ++r){ c0s[m][r] = 0.f; c1s[m][r] = 0.f; }

  __syncthreads();

  const unsigned short* pw0 = pk + SET0 + (w*4)*(5*512) + lane*8;
  const unsigned short* pw1 = pk + SET1 + (w*4)*(8*512) + lane*8;

  // ===================== encoder =====================
  #pragma unroll 1
  for (int t = 0; t < NT; ++t){
    if (t == 8){
      // reload x chunk 1 (t = 8..14); prior xs reads were all before t=7's
      // barriers, so staging here is safe; barrier below protects new reads.
      for (int i = tid; i < 7*64*8; i += 512){
        int k8 = i & 7, r = (i >> 3) & 63, tt = i >> 9;
        u.xs[i] = (k8 < 6) ? f2bf(x[(size_t)(row0 + r)*90 + (8 + tt)*6 + k8])
                           : (unsigned short)0;
      }
      __syncthreads();
    }
    const int tc = t & 7;

    // prefetch L0 weights (global; in flight during ds_reads + barrier)
    short8 w0f[4][5];
    #pragma unroll
    for (int g = 0; g < 4; ++g)
      #pragma unroll
      for (int kt = 0; kt < 5; ++kt)
        w0f[g][kt] = *(const short8*)&pw0[(g*5 + kt)*512];

    // r0: pre-read all hA fragments (hazard: c0 writes hA in place)
    short8 aA[4][4];
    #pragma unroll
    for (int m = 0; m < 4; ++m)
      #pragma unroll
      for (int kt = 0; kt < 4; ++kt)
        aA[m][kt] = *(const short8*)&hA[sidx(m*16 + lidx, kt*32 + lgrp*8)];
    __syncthreads();                       // B1: hA reads complete

    // c0: layer-0 cell, write new h0 into hA in place
    #pragma unroll
    for (int m = 0; m < 4; ++m){
      short8 ax = {0,0,0,0,0,0,0,0};
      if (lgrp == 0) ax = *(const short8*)&u.xs[(tc*64 + m*16 + lidx)*8];
      f32x4 acc[4];
      #pragma unroll
      for (int g = 0; g < 4; ++g){
        f32x4 s = {0.f,0.f,0.f,0.f};
        #pragma unroll
        for (int kt = 0; kt < 4; ++kt)
          s = __builtin_amdgcn_mfma_f32_16x16x32_bf16(aA[m][kt], w0f[g][kt], s, 0, 0, 0);
        s = __builtin_amdgcn_mfma_f32_16x16x32_bf16(ax, w0f[g][4], s, 0, 0, 0);
        acc[g] = s;
      }
      #pragma unroll
      for (int r = 0; r < 4; ++r){
        float iv = sigf(acc[0][r] + b0v[0]);
        float fv = sigf(acc[1][r] + b0v[1]);
        float gv = tanhf_(acc[2][r] + b0v[2]);
        float ov = sigf(acc[3][r] + b0v[3]);
        float c = fv*c0s[m][r] + iv*gv;
        c0s[m][r] = c;
        hA[sidx(m*16 + lgrp*4 + r, col)] = f2bf(ov*tanhf_(c));
      }
    }
    // prefetch L1 weights
    short8 w1f[4][8];
    #pragma unroll
    for (int g = 0; g < 4; ++g)
      #pragma unroll
      for (int kt = 0; kt < 8; ++kt)
        w1f[g][kt] = *(const short8*)&pw1[(g*8 + kt)*512];
    __syncthreads();                       // B2: hA writes complete

    // r1: pre-read all hB fragments (hazard: c1 writes hB in place)
    short8 aH[4][4];
    #pragma unroll
    for (int m = 0; m < 4; ++m)
      #pragma unroll
      for (int kt = 0; kt < 4; ++kt)
        aH[m][kt] = *(const short8*)&hB[sidx(m*16 + lidx, kt*32 + lgrp*8)];
    __syncthreads();                       // B3: hB reads complete

    // c1: layer-1 cell; aI read lazily (hA stable), write hB in place
    #pragma unroll
    for (int m = 0; m < 4; ++m){
      short8 aI[4];
      #pragma unroll
      for (int kt = 0; kt < 4; ++kt)
        aI[kt] = *(const short8*)&hA[sidx(m*16 + lidx, kt*32 + lgrp*8)];
      f32x4 acc[4];
      #pragma unroll
      for (int g = 0; g < 4; ++g){
        f32x4 s = {0.f,0.f,0.f,0.f};
        #pragma unroll
        for (int kt = 0; kt < 4; ++kt)
          s = __builtin_amdgcn_mfma_f32_16x16x32_bf16(aI[kt], w1f[g][kt], s, 0, 0, 0);
        #pragma unroll
        for (int kt = 0; kt < 4; ++kt)
          s = __builtin_amdgcn_mfma_f32_16x16x32_bf16(aH[m][kt], w1f[g][4+kt], s, 0, 0, 0);
        acc[g] = s;
      }
      #pragma unroll
      for (int r = 0; r < 4; ++r){
        float iv = sigf(acc[0][r] + b1v[0]);
        float fv = sigf(acc[1][r] + b1v[1]);
        float gv = tanhf_(acc[2][r] + b1v[2]);
        float ov = sigf(acc[3][r] + b1v[3]);
        float c = fv*c1s[m][r] + iv*gv;
        c1s[m][r] = c;
        hB[sidx(m*16 + lgrp*4 + r, col)] = f2bf(ov*tanhf_(c));
      }
    }
    // no barrier here: next iteration's B1/B2 order hB writes vs hB reads
  }

  // ===================== decoder =====================
  const unsigned short* pw2 = pk + SET2 + (w*4)*(8*512) + lane*8;
  short8 wdf[4][8];
  #pragma unroll
  for (int g = 0; g < 4; ++g)
    #pragma unroll
    for (int kt = 0; kt < 8; ++kt)
      wdf[g][kt] = *(const short8*)&pw2[(g*8 + kt)*512];
  short8 whf[4];
  {
    const short8 z8 = {0,0,0,0,0,0,0,0};
    #pragma unroll
    for (int kt = 0; kt < 4; ++kt) whf[kt] = z8;
    if (w < 4){
      #pragma unroll
      for (int kt = 0; kt < 4; ++kt)
        whf[kt] = *(const short8*)&pk[SET3 + kt*512 + lane*8];
    }
  }
  const float wpa = Wp[col*131 + 0], wpb = Wp[col*131 + 1], wpc = Wp[col*131 + 2];
  const float lngv = lng[col], lnbv = lnb[col];
  float bdv[4];
  #pragma unroll
  for (int g = 0; g < 4; ++g) bdv[g] = bdg[g*128 + col];
  float bmo = 0.f;
  if (lidx < 3) bmo = bm[lidx];
  else if (lidx < 6) bmo = bs[lidx - 3];

  if (tid < 192){
    int r = tid / 3, o = tid - r*3;
    u.d.prevb[r][o] = x[(size_t)(row0 + r)*90 + 14*6 + o];
  }
  __syncthreads();                          // B_pre

  #pragma unroll 1
  for (int s = 0; s < 10; ++s){
    // ph1: dec_in = relu(dbase + prev @ Wp3^T) -> hA
    const float dbs = dbase[s*128 + col];
    #pragma unroll
    for (int m = 0; m < 4; ++m)
      #pragma unroll
      for (int r = 0; r < 4; ++r){
        const int row = m*16 + lgrp*4 + r;
        f32x4 pv = *(const f32x4*)&u.d.prevb[row][0];
        float v = dbs + pv[0]*wpa + pv[1]*wpb + pv[2]*wpc;
        hA[sidx(row, col)] = f2bf(v > 0.f ? v : 0.f);
      }
    __syncthreads();                        // B_f: dec_in visible

    // ph2: pre-read hB fragments, then in-place LSTM cell
    short8 aH[4][4];
    #pragma unroll
    for (int m = 0; m < 4; ++m)
      #pragma unroll
      for (int kt = 0; kt < 4; ++kt)
        aH[m][kt] = *(const short8*)&hB[sidx(m*16 + lidx, kt*32 + lgrp*8)];
    __syncthreads();                        // B_g: hB reads complete

    float hv[4][4];
    #pragma unroll
    for (int m = 0; m < 4; ++m){
      short8 aI[4];
      #pragma unroll
      for (int kt = 0; kt < 4; ++kt)
        aI[kt] = *(const short8*)&hA[sidx(m*16 + lidx, kt*32 + lgrp*8)];
      f32x4 acc[4];
      #pragma unroll
      for (int g = 0; g < 4; ++g){
        f32x4 sa = {0.f,0.f,0.f,0.f};
        #pragma unroll
        for (int kt = 0; kt < 4; ++kt)
          sa = __builtin_amdgcn_mfma_f32_16x16x32_bf16(aI[kt], wdf[g][kt], sa, 0, 0, 0);
        #pragma unroll
        for (int kt = 0; kt < 4; ++kt)
          sa = __builtin_amdgcn_mfma_f32_16x16x32_bf16(aH[m][kt], wdf[g][4+kt], sa, 0, 0, 0);
        acc[g] = sa;
      }
      #pragma unroll
      for (int r = 0; r < 4; ++r){
        float iv = sigf(acc[0][r] + bdv[0]);
        float fv = sigf(acc[1][r] + bdv[1]);
        float gv = tanhf_(acc[2][r] + bdv[2]);
        float ov = sigf(acc[3][r] + bdv[3]);
        float c = fv*c1s[m][r] + iv*gv;
        c1s[m][r] = c;
        float h = ov*tanhf_(c);
        hv[m][r] = h;
        hB[sidx(m*16 + lgrp*4 + r, col)] = f2bf(h);
      }
    }
    // LN partials over this wave's 16 cols
    {
      float s1[4][4], s2[4][4];
      #pragma unroll
      for (int m = 0; m < 4; ++m)
        #pragma unroll
        for (int r = 0; r < 4; ++r){ s1[m][r] = hv[m][r]; s2[m][r] = hv[m][r]*hv[m][r]; }
      #pragma unroll
      for (int d = 1; d < 16; d <<= 1)
        #pragma unroll
        for (int m = 0; m < 4; ++m)
          #pragma unroll
          for (int r = 0; r < 4; ++r){
            s1[m][r] += __shfl_xor(s1[m][r], d);
            s2[m][r] += __shfl_xor(s2[m][r], d);
          }
      if (lidx == 0){
        #pragma unroll
        for (int m = 0; m < 4; ++m)
          #pragma unroll
          for (int r = 0; r < 4; ++r){
            u.d.sred[w][m*16 + lgrp*4 + r][0] = s1[m][r];
            u.d.sred[w][m*16 + lgrp*4 + r][1] = s2[m][r];
          }
      }
    }
    __syncthreads();                        // B_h
    if (tid < 64){
      float ss = 0.f, sq = 0.f;
      #pragma unroll
      for (int ww = 0; ww < 8; ++ww){ ss += u.d.sred[ww][tid][0]; sq += u.d.sred[ww][tid][1]; }
      float mu = ss * (1.f/128.f);
      float var = sq * (1.f/128.f) - mu*mu;
      u.d.mus[tid][0] = mu;
      u.d.mus[tid][1] = __builtin_amdgcn_rsqf(var + 1e-5f);
    }
    __syncthreads();                        // B_i
    // ph4: feat -> hA
    #pragma unroll
    for (int m = 0; m < 4; ++m)
      #pragma unroll
      for (int r = 0; r < 4; ++r){
        const int row = m*16 + lgrp*4 + r;
        float mu = u.d.mus[row][0], rs = u.d.mus[row][1];
        hA[sidx(row, col)] = f2bf((hv[m][r] - mu)*rs*lngv + lnbv);
      }
    __syncthreads();                        // B_j
    // ph5: heads via MFMA (waves 0..3, M-tile = wave)
    if (w < 4){
      short8 a[4];
      #pragma unroll
      for (int kt = 0; kt < 4; ++kt)
        a[kt] = *(const short8*)&hA[sidx(w*16 + lidx, kt*32 + lgrp*8)];
      f32x4 acc = {0.f,0.f,0.f,0.f};
      #pragma unroll
      for (int kt = 0; kt < 4; ++kt)
        acc = __builtin_amdgcn_mfma_f32_16x16x32_bf16(a[kt], whf[kt], acc, 0, 0, 0);
      #pragma unroll
      for (int r = 0; r < 4; ++r){
        const int row = w*16 + lgrp*4 + r;
        float v = acc[r] + bmo;
        if (lidx < 3){
          out[(size_t)(row0 + row)*30 + s*3 + lidx] = v;
          u.d.prevb[row][lidx] = v;
        } else if (lidx < 6){
          out[(size_t)65536*30 + (size_t)(row0 + row)*30 + s*3 + (lidx - 3)] =
              fminf(fmaxf(v, -6.f), 3.f);
        }
      }
    }
    __syncthreads();                        // B_e
  }
}

extern "C" void kernel_launch(void* const* d_in, const int* in_sizes, int n_in,
                              void* d_out, int out_size, void* d_ws, size_t ws_size,
                              hipStream_t stream)
{
  const float* x    = (const float*)d_in[0];
  const float* Wih0 = (const float*)d_in[1];
  const float* Whh0 = (const float*)d_in[2];
  const float* b0   = (const float*)d_in[3];
  const float* Wih1 = (const float*)d_in[4];
  const float* Whh1 = (const float*)d_in[5];
  const float* b1   = (const float*)d_in[6];
  const float* Wihd = (const float*)d_in[7];
  const float* Whhd = (const float*)d_in[8];
  const float* bd   = (const float*)d_in[9];
  const float* emb  = (const float*)d_in[10];
  const float* Wp   = (const float*)d_in[11];
  const float* bp   = (const float*)d_in[12];
  const float* Wm   = (const float*)d_in[13];
  const float* bm   = (const float*)d_in[14];
  const float* Ws   = (const float*)d_in[15];
  const float* bs   = (const float*)d_in[16];
  const float* lng  = (const float*)d_in[17];
  const float* lnb  = (const float*)d_in[18];

  unsigned short* pkw = (unsigned short*)d_ws;
  float* dbase = (float*)((char*)d_ws + DBASE_OFF);

  pack_w<<<(PK_TOTAL + 255)/256, 256, 0, stream>>>(Wih0, Whh0, Wih1, Whh1,
                                                   Wihd, Whhd, Wm, Ws, pkw);
  prep_decbase<<<10, 128, 0, stream>>>(emb, Wp, bp, dbase);
  traj_main<<<1024, 512, 0, stream>>>(x, pkw, dbase, b0, b1, bd, Wp,
                                      bm, bs, lng, lnb, (float*)d_out);
}

// Round 4
// 2535.300 us; speedup vs baseline: 3.3060x; 3.3060x over previous
//
#include <hip/hip_runtime.h>
#include <stdint.h>

typedef __attribute__((ext_vector_type(8))) short short8;
typedef __attribute__((ext_vector_type(4))) float f32x4;

#define NT 15

// packed bf16 weight fragments in d_ws (element offsets, shorts)
#define SET0 0          // L0: 32 (jt,g) pairs x 5 kt x 512
#define SET1 81920      // L1: 32 pairs x 8 kt x 512
#define SET2 212992     // dec: same shape as L1
#define SET3 344064     // heads [Wm;Ws]: 4 kt x 512
#define PK_TOTAL 346112
#define DBASE_OFF (PK_TOTAL*2)   // byte offset of dbase in ws

__device__ __forceinline__ unsigned short f2bf(float f){
  unsigned int u = __builtin_bit_cast(unsigned int, f);
  u += 0x7fffu + ((u >> 16) & 1u);
  return (unsigned short)(u >> 16);
}
__device__ __forceinline__ float sigf(float x){
  return __builtin_amdgcn_rcpf(1.0f + __expf(-x));
}
__device__ __forceinline__ float tanhf_(float x){
  return 1.0f - 2.0f*__builtin_amdgcn_rcpf(1.0f + __expf(2.0f*x));
}
// XOR-swizzled LDS index (shorts): spreads stride-256B rows across banks.
__device__ __forceinline__ int sidx(int row, int col){
  return row*128 + (col ^ ((row & 7) << 3));
}

// ---------------- prep: pack weights to bf16 MFMA fragments ----------------
// Fragment (n,k): lane holds n = 16-col tile + (lane&15), k = kt*32+(lane>>4)*8+j.
__global__ void pack_w(const float* __restrict__ Wih0, const float* __restrict__ Whh0,
                       const float* __restrict__ Wih1, const float* __restrict__ Whh1,
                       const float* __restrict__ Wihd, const float* __restrict__ Whhd,
                       const float* __restrict__ Wm,  const float* __restrict__ Ws,
                       unsigned short* __restrict__ pk)
{
  int idx = blockIdx.x*256 + threadIdx.x;
  if (idx >= PK_TOTAL) return;
  float v = 0.f;
  if (idx >= SET3){
    int e = idx - SET3;
    int j = e & 7, lane = (e >> 3) & 63, kt = e >> 9;
    int n = lane & 15;
    int k = kt*32 + (lane >> 4)*8 + j;
    if (n < 3) v = Wm[n*128 + k];
    else if (n < 6) v = Ws[(n-3)*128 + k];
  } else {
    int set, e;
    if (idx < SET1){ set = 0; e = idx; }
    else if (idx < SET2){ set = 1; e = idx - SET1; }
    else { set = 2; e = idx - SET2; }
    int j = e & 7, lane = (e >> 3) & 63, rest = e >> 9;
    int nf = (set == 0) ? 5 : 8;
    int kt = rest % nf, pair = rest / nf;
    int g = pair & 3, jt = pair >> 2;
    int n = g*128 + jt*16 + (lane & 15);
    int kk = (lane >> 4)*8 + j;
    if (set == 0){
      if (kt < 4) v = Whh0[n*128 + kt*32 + kk];          // K 0..127 = h0
      else if (kk < 6) v = Wih0[n*6 + kk];               // K-ext tile = x
    } else {
      const float* Wi = (set == 1) ? Wih1 : Wihd;
      const float* Wh = (set == 1) ? Whh1 : Whhd;
      v = (kt < 4) ? Wi[n*128 + kt*32 + kk] : Wh[n*128 + (kt-4)*32 + kk];
    }
  }
  pk[idx] = f2bf(v);
}

// dec_base[s][j] = bp[j] + sum_k emb[s][k]*Wp[j][3+k]
__global__ void prep_decbase(const float* __restrict__ emb, const float* __restrict__ Wp,
                             const float* __restrict__ bp, float* __restrict__ dbase)
{
  int idx = blockIdx.x*128 + threadIdx.x;
  if (idx >= 1280) return;
  int s = idx >> 7, j = idx & 127;
  float acc = bp[j];
  for (int k = 0; k < 128; ++k) acc += emb[s*128 + k] * Wp[j*131 + 3 + k];
  dbase[idx] = acc;
}

union DecShared {
  unsigned short xs[8*64*8];                  // 8192 B: x chunk [tt][row][8]
  struct {
    float sred[8][64][2];                     // LN partials per wave
    float mus[64][2];                         // mu, rstd per row
    float prevb[64][4];                       // prev-mu broadcast
  } d;
};

// ---------------- main fused kernel ----------------
// 512 thr = 8 waves; block owns 64 rows; wave w owns gate-columns [w*16,w*16+16)
// (all 4 gates). Double-buffered LDS; x staged in two 8-step chunks so
// LDS = 73728 B -> 2 blocks/CU (round 2's 80896 B allowed only 1).
__global__ __launch_bounds__(512)
void traj_main(const float* __restrict__ x,
               const unsigned short* __restrict__ pk,
               const float* __restrict__ dbase,
               const float* __restrict__ b0g, const float* __restrict__ b1g,
               const float* __restrict__ bdg,
               const float* __restrict__ Wp,
               const float* __restrict__ bm, const float* __restrict__ bs,
               const float* __restrict__ lng, const float* __restrict__ lnb,
               float* __restrict__ out)
{
  __shared__ __align__(16) unsigned short hA[2][64*128];
  __shared__ __align__(16) unsigned short hB[2][64*128];
  __shared__ __align__(16) DecShared u;

  const int tid  = threadIdx.x;
  const int w    = tid >> 6;
  const int lane = tid & 63;
  const int lidx = lane & 15;
  const int lgrp = lane >> 4;
  const int col  = w*16 + lidx;
  const int row0 = blockIdx.x * 64;

  for (int i = tid; i < 64*128; i += 512){ hA[0][i] = 0; hB[0][i] = 0; }
  // stage x chunk 0 (t = 0..7)
  for (int i = tid; i < 8*64*8; i += 512){
    int k8 = i & 7, r = (i >> 3) & 63, tt = i >> 9;
    u.xs[i] = (k8 < 6) ? f2bf(x[(size_t)(row0 + r)*90 + tt*6 + k8]) : (unsigned short)0;
  }

  float b0v[4], b1v[4];
  #pragma unroll
  for (int g = 0; g < 4; ++g){ b0v[g] = b0g[g*128 + col]; b1v[g] = b1g[g*128 + col]; }

  float c0[4][4], c1[4][4];
  #pragma unroll
  for (int m = 0; m < 4; ++m)
    #pragma unroll
    for (int r = 0; r < 4; ++r){ c0[m][r] = 0.f; c1[m][r] = 0.f; }

  __syncthreads();

  const unsigned short* pw0 = pk + SET0 + (w*4)*(5*512) + lane*8;
  const unsigned short* pw1 = pk + SET1 + (w*4)*(8*512) + lane*8;

  int ca = 0, cb = 0;
  #pragma unroll 1
  for (int t = 0; t < NT; ++t){
    if (t == 8){
      // all waves are past t=7 entirely (iteration ends with a barrier),
      // so xs can be restaged; barrier below makes it visible.
      for (int i = tid; i < 7*64*8; i += 512){
        int k8 = i & 7, r = (i >> 3) & 63, tt = i >> 9;
        u.xs[i] = (k8 < 6) ? f2bf(x[(size_t)(row0 + r)*90 + (8 + tt)*6 + k8])
                           : (unsigned short)0;
      }
      __syncthreads();
    }
    const int tc = t & 7;
    // ---------- layer 0: [h0 | x_t] @ W^T ----------
    short8 w0f[4][5];
    #pragma unroll
    for (int g = 0; g < 4; ++g)
      #pragma unroll
      for (int kt = 0; kt < 5; ++kt)
        w0f[g][kt] = *(const short8*)&pw0[(g*5 + kt)*512];
    #pragma unroll
    for (int m = 0; m < 4; ++m){
      const int arow = m*16 + lidx;
      short8 a[5];
      #pragma unroll
      for (int kt = 0; kt < 4; ++kt)
        a[kt] = *(const short8*)&hA[ca][sidx(arow, kt*32 + lgrp*8)];
      short8 ax = {0,0,0,0,0,0,0,0};
      if (lgrp == 0) ax = *(const short8*)&u.xs[(tc*64 + arow)*8];
      a[4] = ax;
      f32x4 acc[4];
      #pragma unroll
      for (int g = 0; g < 4; ++g){
        f32x4 s = {0.f,0.f,0.f,0.f};
        #pragma unroll
        for (int kt = 0; kt < 5; ++kt)
          s = __builtin_amdgcn_mfma_f32_16x16x32_bf16(a[kt], w0f[g][kt], s, 0, 0, 0);
        acc[g] = s;
      }
      #pragma unroll
      for (int r = 0; r < 4; ++r){
        float iv = sigf(acc[0][r] + b0v[0]);
        float fv = sigf(acc[1][r] + b0v[1]);
        float gv = tanhf_(acc[2][r] + b0v[2]);
        float ov = sigf(acc[3][r] + b0v[3]);
        float c = fv*c0[m][r] + iv*gv;
        c0[m][r] = c;
        hA[ca^1][sidx(m*16 + lgrp*4 + r, col)] = f2bf(ov*tanhf_(c));
      }
    }
    __syncthreads();
    // ---------- layer 1: [h0_new | h1] @ W^T ----------
    short8 w1f[4][8];
    #pragma unroll
    for (int g = 0; g < 4; ++g)
      #pragma unroll
      for (int kt = 0; kt < 8; ++kt)
        w1f[g][kt] = *(const short8*)&pw1[(g*8 + kt)*512];
    #pragma unroll
    for (int m = 0; m < 4; ++m){
      const int arow = m*16 + lidx;
      short8 a[8];
      #pragma unroll
      for (int kt = 0; kt < 4; ++kt)
        a[kt] = *(const short8*)&hA[ca^1][sidx(arow, kt*32 + lgrp*8)];
      #pragma unroll
      for (int kt = 0; kt < 4; ++kt)
        a[4+kt] = *(const short8*)&hB[cb][sidx(arow, kt*32 + lgrp*8)];
      f32x4 acc[4];
      #pragma unroll
      for (int g = 0; g < 4; ++g){
        f32x4 s = {0.f,0.f,0.f,0.f};
        #pragma unroll
        for (int kt = 0; kt < 8; ++kt)
          s = __builtin_amdgcn_mfma_f32_16x16x32_bf16(a[kt], w1f[g][kt], s, 0, 0, 0);
        acc[g] = s;
      }
      #pragma unroll
      for (int r = 0; r < 4; ++r){
        float iv = sigf(acc[0][r] + b1v[0]);
        float fv = sigf(acc[1][r] + b1v[1]);
        float gv = tanhf_(acc[2][r] + b1v[2]);
        float ov = sigf(acc[3][r] + b1v[3]);
        float c = fv*c1[m][r] + iv*gv;
        c1[m][r] = c;
        hB[cb^1][sidx(m*16 + lgrp*4 + r, col)] = f2bf(ov*tanhf_(c));
      }
    }
    __syncthreads();
    ca ^= 1; cb ^= 1;
  }

  // ===================== decoder =====================
  const unsigned short* pw2 = pk + SET2 + (w*4)*(8*512) + lane*8;
  short8 wdf[4][8];
  #pragma unroll
  for (int g = 0; g < 4; ++g)
    #pragma unroll
    for (int kt = 0; kt < 8; ++kt)
      wdf[g][kt] = *(const short8*)&pw2[(g*8 + kt)*512];
  short8 whf[4];
  {
    const short8 z8 = {0,0,0,0,0,0,0,0};
    #pragma unroll
    for (int kt = 0; kt < 4; ++kt) whf[kt] = z8;
    if (w < 4){
      #pragma unroll
      for (int kt = 0; kt < 4; ++kt)
        whf[kt] = *(const short8*)&pk[SET3 + kt*512 + lane*8];
    }
  }

  const float wpa = Wp[col*131 + 0], wpb = Wp[col*131 + 1], wpc = Wp[col*131 + 2];
  const float lngv = lng[col], lnbv = lnb[col];
  float bdv[4];
  #pragma unroll
  for (int g = 0; g < 4; ++g) bdv[g] = bdg[g*128 + col];
  float bmo = 0.f;
  if (lidx < 3) bmo = bm[lidx];
  else if (lidx < 6) bmo = bs[lidx - 3];

  if (tid < 192){
    int r = tid / 3, o = tid - r*3;
    u.d.prevb[r][o] = x[(size_t)(row0 + r)*90 + 14*6 + o];
  }
  __syncthreads();

  int cbd = 1;   // h1 lives in hB[1] after 15 toggles
  #pragma unroll 1
  for (int s = 0; s < 10; ++s){
    // ph1: dec_in = relu(dbase + prev @ Wp3^T) -> hA[0]
    const float dbs = dbase[s*128 + col];
    #pragma unroll
    for (int m = 0; m < 4; ++m)
      #pragma unroll
      for (int r = 0; r < 4; ++r){
        const int row = m*16 + lgrp*4 + r;
        f32x4 pv = *(const f32x4*)&u.d.prevb[row][0];
        float v = dbs + pv[0]*wpa + pv[1]*wpb + pv[2]*wpc;
        hA[0][sidx(row, col)] = f2bf(v > 0.f ? v : 0.f);
      }
    __syncthreads();

    // ph2: LSTM cell
    float hv[4][4];
    #pragma unroll
    for (int m = 0; m < 4; ++m){
      const int arow = m*16 + lidx;
      short8 a[8];
      #pragma unroll
      for (int kt = 0; kt < 4; ++kt)
        a[kt] = *(const short8*)&hA[0][sidx(arow, kt*32 + lgrp*8)];
      #pragma unroll
      for (int kt = 0; kt < 4; ++kt)
        a[4+kt] = *(const short8*)&hB[cbd][sidx(arow, kt*32 + lgrp*8)];
      f32x4 acc[4];
      #pragma unroll
      for (int g = 0; g < 4; ++g){
        f32x4 sa = {0.f,0.f,0.f,0.f};
        #pragma unroll
        for (int kt = 0; kt < 8; ++kt)
          sa = __builtin_amdgcn_mfma_f32_16x16x32_bf16(a[kt], wdf[g][kt], sa, 0, 0, 0);
        acc[g] = sa;
      }
      #pragma unroll
      for (int r = 0; r < 4; ++r){
        float iv = sigf(acc[0][r] + bdv[0]);
        float fv = sigf(acc[1][r] + bdv[1]);
        float gv = tanhf_(acc[2][r] + bdv[2]);
        float ov = sigf(acc[3][r] + bdv[3]);
        float c = fv*c1[m][r] + iv*gv;
        c1[m][r] = c;
        float h = ov*tanhf_(c);
        hv[m][r] = h;
        hB[cbd^1][sidx(m*16 + lgrp*4 + r, col)] = f2bf(h);
      }
    }
    // LN partials over this wave's 16 cols (reduce across lidx)
    {
      float s1[4][4], s2[4][4];
      #pragma unroll
      for (int m = 0; m < 4; ++m)
        #pragma unroll
        for (int r = 0; r < 4; ++r){ s1[m][r] = hv[m][r]; s2[m][r] = hv[m][r]*hv[m][r]; }
      #pragma unroll
      for (int d = 1; d < 16; d <<= 1)
        #pragma unroll
        for (int m = 0; m < 4; ++m)
          #pragma unroll
          for (int r = 0; r < 4; ++r){
            s1[m][r] += __shfl_xor(s1[m][r], d);
            s2[m][r] += __shfl_xor(s2[m][r], d);
          }
      if (lidx == 0){
        #pragma unroll
        for (int m = 0; m < 4; ++m)
          #pragma unroll
          for (int r = 0; r < 4; ++r){
            u.d.sred[w][m*16 + lgrp*4 + r][0] = s1[m][r];
            u.d.sred[w][m*16 + lgrp*4 + r][1] = s2[m][r];
          }
      }
    }
    __syncthreads();
    // ph3: finalize LN stats
    if (tid < 64){
      float ss = 0.f, sq = 0.f;
      #pragma unroll
      for (int ww = 0; ww < 8; ++ww){ ss += u.d.sred[ww][tid][0]; sq += u.d.sred[ww][tid][1]; }
      float mu = ss * (1.f/128.f);
      float var = sq * (1.f/128.f) - mu*mu;
      u.d.mus[tid][0] = mu;
      u.d.mus[tid][1] = __builtin_amdgcn_rsqf(var + 1e-5f);
    }
    __syncthreads();
    // ph4: feat -> hA[0] (overwrites dec_in)
    #pragma unroll
    for (int m = 0; m < 4; ++m)
      #pragma unroll
      for (int r = 0; r < 4; ++r){
        const int row = m*16 + lgrp*4 + r;
        float mu = u.d.mus[row][0], rs = u.d.mus[row][1];
        hA[0][sidx(row, col)] = f2bf((hv[m][r] - mu)*rs*lngv + lnbv);
      }
    __syncthreads();
    // ph5: heads via MFMA (waves 0..3, M-tile = wave)
    if (w < 4){
      const int arow = w*16 + lidx;
      short8 a[4];
      #pragma unroll
      for (int kt = 0; kt < 4; ++kt)
        a[kt] = *(const short8*)&hA[0][sidx(arow, kt*32 + lgrp*8)];
      f32x4 acc = {0.f,0.f,0.f,0.f};
      #pragma unroll
      for (int kt = 0; kt < 4; ++kt)
        acc = __builtin_amdgcn_mfma_f32_16x16x32_bf16(a[kt], whf[kt], acc, 0, 0, 0);
      #pragma unroll
      for (int r = 0; r < 4; ++r){
        const int row = w*16 + lgrp*4 + r;
        float v = acc[r] + bmo;
        if (lidx < 3){
          out[(size_t)(row0 + row)*30 + s*3 + lidx] = v;
          u.d.prevb[row][lidx] = v;
        } else if (lidx < 6){
          out[(size_t)65536*30 + (size_t)(row0 + row)*30 + s*3 + (lidx - 3)] =
              fminf(fmaxf(v, -6.f), 3.f);
        }
      }
    }
    __syncthreads();
    cbd ^= 1;
  }
}

extern "C" void kernel_launch(void* const* d_in, const int* in_sizes, int n_in,
                              void* d_out, int out_size, void* d_ws, size_t ws_size,
                              hipStream_t stream)
{
  const float* x    = (const float*)d_in[0];
  const float* Wih0 = (const float*)d_in[1];
  const float* Whh0 = (const float*)d_in[2];
  const float* b0   = (const float*)d_in[3];
  const float* Wih1 = (const float*)d_in[4];
  const float* Whh1 = (const float*)d_in[5];
  const float* b1   = (const float*)d_in[6];
  const float* Wihd = (const float*)d_in[7];
  const float* Whhd = (const float*)d_in[8];
  const float* bd   = (const float*)d_in[9];
  const float* emb  = (const float*)d_in[10];
  const float* Wp   = (const float*)d_in[11];
  const float* bp   = (const float*)d_in[12];
  const float* Wm   = (const float*)d_in[13];
  const float* bm   = (const float*)d_in[14];
  const float* Ws   = (const float*)d_in[15];
  const float* bs   = (const float*)d_in[16];
  const float* lng  = (const float*)d_in[17];
  const float* lnb  = (const float*)d_in[18];

  unsigned short* pkw = (unsigned short*)d_ws;
  float* dbase = (float*)((char*)d_ws + DBASE_OFF);

  pack_w<<<(PK_TOTAL + 255)/256, 256, 0, stream>>>(Wih0, Whh0, Wih1, Whh1,
                                                   Wihd, Whhd, Wm, Ws, pkw);
  prep_decbase<<<10, 128, 0, stream>>>(emb, Wp, bp, dbase);
  traj_main<<<1024, 512, 0, stream>>>(x, pkw, dbase, b0, b1, bd, Wp,
                                      bm, bs, lng, lnb, (float*)d_out);
}

// Round 5
// 2374.191 us; speedup vs baseline: 3.5303x; 1.0679x over previous
//
#include <hip/hip_runtime.h>
#include <stdint.h>

typedef __attribute__((ext_vector_type(8))) short short8;
typedef __attribute__((ext_vector_type(4))) float f32x4;

#define NT 15

// packed bf16 weight fragments in d_ws (element offsets, shorts)
#define SET0 0          // L0: 32 (jt,g) pairs x 5 kt x 512
#define SET1 81920      // L1: 32 pairs x 8 kt x 512
#define SET2 212992     // dec: same shape as L1
#define SET3 344064     // heads [Wm;Ws]: 4 kt x 512
#define PK_TOTAL 346112
#define DBASE_OFF (PK_TOTAL*2)   // byte offset of dbase in ws

__device__ __forceinline__ unsigned short f2bf(float f){
  unsigned int u = __builtin_bit_cast(unsigned int, f);
  u += 0x7fffu + ((u >> 16) & 1u);
  return (unsigned short)(u >> 16);
}
__device__ __forceinline__ float sigf(float x){
  return __builtin_amdgcn_rcpf(1.0f + __expf(-x));
}
__device__ __forceinline__ float tanhf_(float x){
  return 1.0f - 2.0f*__builtin_amdgcn_rcpf(1.0f + __expf(2.0f*x));
}
// XOR-swizzled LDS index (shorts): spreads stride-256B rows across banks.
__device__ __forceinline__ int sidx(int row, int col){
  return row*128 + (col ^ ((row & 7) << 3));
}

// ---------------- prep: pack weights to bf16 MFMA fragments ----------------
// Fragment (n,k): lane holds n = 16-col tile + (lane&15), k = kt*32+(lane>>4)*8+j.
__global__ void pack_w(const float* __restrict__ Wih0, const float* __restrict__ Whh0,
                       const float* __restrict__ Wih1, const float* __restrict__ Whh1,
                       const float* __restrict__ Wihd, const float* __restrict__ Whhd,
                       const float* __restrict__ Wm,  const float* __restrict__ Ws,
                       unsigned short* __restrict__ pk)
{
  int idx = blockIdx.x*256 + threadIdx.x;
  if (idx >= PK_TOTAL) return;
  float v = 0.f;
  if (idx >= SET3){
    int e = idx - SET3;
    int j = e & 7, lane = (e >> 3) & 63, kt = e >> 9;
    int n = lane & 15;
    int k = kt*32 + (lane >> 4)*8 + j;
    if (n < 3) v = Wm[n*128 + k];
    else if (n < 6) v = Ws[(n-3)*128 + k];
  } else {
    int set, e;
    if (idx < SET1){ set = 0; e = idx; }
    else if (idx < SET2){ set = 1; e = idx - SET1; }
    else { set = 2; e = idx - SET2; }
    int j = e & 7, lane = (e >> 3) & 63, rest = e >> 9;
    int nf = (set == 0) ? 5 : 8;
    int kt = rest % nf, pair = rest / nf;
    int g = pair & 3, jt = pair >> 2;
    int n = g*128 + jt*16 + (lane & 15);
    int kk = (lane >> 4)*8 + j;
    if (set == 0){
      if (kt < 4) v = Whh0[n*128 + kt*32 + kk];          // K 0..127 = h0
      else if (kk < 6) v = Wih0[n*6 + kk];               // K-ext tile = x
    } else {
      const float* Wi = (set == 1) ? Wih1 : Wihd;
      const float* Wh = (set == 1) ? Whh1 : Whhd;
      v = (kt < 4) ? Wi[n*128 + kt*32 + kk] : Wh[n*128 + (kt-4)*32 + kk];
    }
  }
  pk[idx] = f2bf(v);
}

// dec_base[s][j] = bp[j] + sum_k emb[s][k]*Wp[j][3+k]
__global__ void prep_decbase(const float* __restrict__ emb, const float* __restrict__ Wp,
                             const float* __restrict__ bp, float* __restrict__ dbase)
{
  int idx = blockIdx.x*128 + threadIdx.x;
  if (idx >= 1280) return;
  int s = idx >> 7, j = idx & 127;
  float acc = bp[j];
  for (int k = 0; k < 128; ++k) acc += emb[s*128 + k] * Wp[j*131 + 3 + k];
  dbase[idx] = acc;
}

// ---------------- main fused kernel ----------------
// 512 thr = 8 waves; block owns 64 rows; wave w owns gate-columns [w*16,w*16+16)
// (all 4 gates). THREE rotating 16KB LDS h-buffers (old-h0 slot is dead after
// the L0->L1 barrier, so L1 writes new-h1 there). x-fragment loaded straight
// from global (L2-hot). LDS total 54784 B -> 2 blocks/CU under a ~110-128KB
// usable pool (round-3/4 evidence: pool >= 120KB but < 147KB).
__global__ __launch_bounds__(512)
void traj_main(const float* __restrict__ x,
               const unsigned short* __restrict__ pk,
               const float* __restrict__ dbase,
               const float* __restrict__ b0g, const float* __restrict__ b1g,
               const float* __restrict__ bdg,
               const float* __restrict__ Wp,
               const float* __restrict__ bm, const float* __restrict__ bs,
               const float* __restrict__ lng, const float* __restrict__ lnb,
               float* __restrict__ out)
{
  __shared__ __align__(16) unsigned short hP[3][64*128];
  __shared__ __align__(16) struct {
    float sred[8][64][2];                     // LN partials per wave
    float mus[64][2];                         // mu, rstd per row
    float prevb[64][4];                       // prev-mu broadcast
  } u;

  const int tid  = threadIdx.x;
  const int w    = tid >> 6;
  const int lane = tid & 63;
  const int lidx = lane & 15;
  const int lgrp = lane >> 4;
  const int col  = w*16 + lidx;
  const int row0 = blockIdx.x * 64;

  for (int i = tid; i < 64*128; i += 512){ hP[0][i] = 0; hP[1][i] = 0; }

  float b0v[4], b1v[4];
  #pragma unroll
  for (int g = 0; g < 4; ++g){ b0v[g] = b0g[g*128 + col]; b1v[g] = b1g[g*128 + col]; }

  float c0[4][4], c1[4][4];
  #pragma unroll
  for (int m = 0; m < 4; ++m)
    #pragma unroll
    for (int r = 0; r < 4; ++r){ c0[m][r] = 0.f; c1[m][r] = 0.f; }

  __syncthreads();

  const unsigned short* pw0 = pk + SET0 + (w*4)*(5*512) + lane*8;
  const unsigned short* pw1 = pk + SET1 + (w*4)*(8*512) + lane*8;

  int i0 = 0, i1 = 1, ifr = 2;
  #pragma unroll 1
  for (int t = 0; t < NT; ++t){
    const unsigned short* bh0 = &hP[i0][0];
    const unsigned short* bh1 = &hP[i1][0];
    unsigned short*       bnw = &hP[ifr][0];

    // ---------- layer 0: [h0 | x_t] @ W^T ; read bh0, write bnw ----------
    short8 w0f[4][5];
    #pragma unroll
    for (int g = 0; g < 4; ++g)
      #pragma unroll
      for (int kt = 0; kt < 5; ++kt)
        w0f[g][kt] = *(const short8*)&pw0[(g*5 + kt)*512];
    #pragma unroll
    for (int m = 0; m < 4; ++m){
      const int arow = m*16 + lidx;
      short8 a[5];
      #pragma unroll
      for (int kt = 0; kt < 4; ++kt)
        a[kt] = *(const short8*)&bh0[sidx(arow, kt*32 + lgrp*8)];
      short8 ax = {0,0,0,0,0,0,0,0};
      if (lgrp == 0){
        const float* xp = &x[(size_t)(row0 + arow)*90 + t*6];
        #pragma unroll
        for (int j = 0; j < 6; ++j) ax[j] = (short)f2bf(xp[j]);
      }
      a[4] = ax;
      f32x4 acc[4];
      #pragma unroll
      for (int g = 0; g < 4; ++g){
        f32x4 s = {0.f,0.f,0.f,0.f};
        #pragma unroll
        for (int kt = 0; kt < 5; ++kt)
          s = __builtin_amdgcn_mfma_f32_16x16x32_bf16(a[kt], w0f[g][kt], s, 0, 0, 0);
        acc[g] = s;
      }
      #pragma unroll
      for (int r = 0; r < 4; ++r){
        float iv = sigf(acc[0][r] + b0v[0]);
        float fv = sigf(acc[1][r] + b0v[1]);
        float gv = tanhf_(acc[2][r] + b0v[2]);
        float ov = sigf(acc[3][r] + b0v[3]);
        float c = fv*c0[m][r] + iv*gv;
        c0[m][r] = c;
        bnw[sidx(m*16 + lgrp*4 + r, col)] = f2bf(ov*tanhf_(c));
      }
    }
    __syncthreads();   // bnw (new h0) visible; bh0 now dead

    // ---------- layer 1: [h0_new | h1] @ W^T ; read bnw,bh1, write bh0 ----------
    short8 w1f[4][8];
    #pragma unroll
    for (int g = 0; g < 4; ++g)
      #pragma unroll
      for (int kt = 0; kt < 8; ++kt)
        w1f[g][kt] = *(const short8*)&pw1[(g*8 + kt)*512];
    #pragma unroll
    for (int m = 0; m < 4; ++m){
      const int arow = m*16 + lidx;
      short8 a[8];
      #pragma unroll
      for (int kt = 0; kt < 4; ++kt)
        a[kt] = *(const short8*)&bnw[sidx(arow, kt*32 + lgrp*8)];
      #pragma unroll
      for (int kt = 0; kt < 4; ++kt)
        a[4+kt] = *(const short8*)&bh1[sidx(arow, kt*32 + lgrp*8)];
      f32x4 acc[4];
      #pragma unroll
      for (int g = 0; g < 4; ++g){
        f32x4 s = {0.f,0.f,0.f,0.f};
        #pragma unroll
        for (int kt = 0; kt < 8; ++kt)
          s = __builtin_amdgcn_mfma_f32_16x16x32_bf16(a[kt], w1f[g][kt], s, 0, 0, 0);
        acc[g] = s;
      }
      #pragma unroll
      for (int r = 0; r < 4; ++r){
        float iv = sigf(acc[0][r] + b1v[0]);
        float fv = sigf(acc[1][r] + b1v[1]);
        float gv = tanhf_(acc[2][r] + b1v[2]);
        float ov = sigf(acc[3][r] + b1v[3]);
        float c = fv*c1[m][r] + iv*gv;
        c1[m][r] = c;
        const_cast<unsigned short*>(bh0)[sidx(m*16 + lgrp*4 + r, col)] =
            f2bf(ov*tanhf_(c));
      }
    }
    __syncthreads();   // new h1 (in old-h0 slot) visible
    // rotate roles: h0' = ifr, h1' = i0, free' = i1
    int t0 = i0; i0 = ifr; ifr = i1; i1 = t0;
  }
  // after 15 steps (period 3): (i0,i1,ifr) = (0,1,2); h1 in buffer 1.

  // ===================== decoder =====================
  const unsigned short* pw2 = pk + SET2 + (w*4)*(8*512) + lane*8;
  short8 wdf[4][8];
  #pragma unroll
  for (int g = 0; g < 4; ++g)
    #pragma unroll
    for (int kt = 0; kt < 8; ++kt)
      wdf[g][kt] = *(const short8*)&pw2[(g*8 + kt)*512];
  short8 whf[4];
  {
    const short8 z8 = {0,0,0,0,0,0,0,0};
    #pragma unroll
    for (int kt = 0; kt < 4; ++kt) whf[kt] = z8;
    if (w < 4){
      #pragma unroll
      for (int kt = 0; kt < 4; ++kt)
        whf[kt] = *(const short8*)&pk[SET3 + kt*512 + lane*8];
    }
  }

  const float wpa = Wp[col*131 + 0], wpb = Wp[col*131 + 1], wpc = Wp[col*131 + 2];
  const float lngv = lng[col], lnbv = lnb[col];
  float bdv[4];
  #pragma unroll
  for (int g = 0; g < 4; ++g) bdv[g] = bdg[g*128 + col];
  float bmo = 0.f;
  if (lidx < 3) bmo = bm[lidx];
  else if (lidx < 6) bmo = bs[lidx - 3];

  if (tid < 192){
    int r = tid / 3, o = tid - r*3;
    u.prevb[r][o] = x[(size_t)(row0 + r)*90 + 14*6 + o];
  }
  __syncthreads();

  int hcur = 1, hnew = 0;          // h1 buffer / target; hP[2] = din & feat
  #pragma unroll 1
  for (int s = 0; s < 10; ++s){
    unsigned short* bdin = &hP[2][0];
    const unsigned short* bh = &hP[hcur][0];
    unsigned short* bhn = &hP[hnew][0];

    // ph1: dec_in = relu(dbase + prev @ Wp3^T) -> hP[2]
    const float dbs = dbase[s*128 + col];
    #pragma unroll
    for (int m = 0; m < 4; ++m)
      #pragma unroll
      for (int r = 0; r < 4; ++r){
        const int row = m*16 + lgrp*4 + r;
        f32x4 pv = *(const f32x4*)&u.prevb[row][0];
        float v = dbs + pv[0]*wpa + pv[1]*wpb + pv[2]*wpc;
        bdin[sidx(row, col)] = f2bf(v > 0.f ? v : 0.f);
      }
    __syncthreads();

    // ph2: LSTM cell; read hP[2]+bh, write bhn
    float hv[4][4];
    #pragma unroll
    for (int m = 0; m < 4; ++m){
      const int arow = m*16 + lidx;
      short8 a[8];
      #pragma unroll
      for (int kt = 0; kt < 4; ++kt)
        a[kt] = *(const short8*)&bdin[sidx(arow, kt*32 + lgrp*8)];
      #pragma unroll
      for (int kt = 0; kt < 4; ++kt)
        a[4+kt] = *(const short8*)&bh[sidx(arow, kt*32 + lgrp*8)];
      f32x4 acc[4];
      #pragma unroll
      for (int g = 0; g < 4; ++g){
        f32x4 sa = {0.f,0.f,0.f,0.f};
        #pragma unroll
        for (int kt = 0; kt < 8; ++kt)
          sa = __builtin_amdgcn_mfma_f32_16x16x32_bf16(a[kt], wdf[g][kt], sa, 0, 0, 0);
        acc[g] = sa;
      }
      #pragma unroll
      for (int r = 0; r < 4; ++r){
        float iv = sigf(acc[0][r] + bdv[0]);
        float fv = sigf(acc[1][r] + bdv[1]);
        float gv = tanhf_(acc[2][r] + bdv[2]);
        float ov = sigf(acc[3][r] + bdv[3]);
        float c = fv*c1[m][r] + iv*gv;
        c1[m][r] = c;
        float h = ov*tanhf_(c);
        hv[m][r] = h;
        bhn[sidx(m*16 + lgrp*4 + r, col)] = f2bf(h);
      }
    }
    // LN partials over this wave's 16 cols (reduce across lidx)
    {
      float s1[4][4], s2[4][4];
      #pragma unroll
      for (int m = 0; m < 4; ++m)
        #pragma unroll
        for (int r = 0; r < 4; ++r){ s1[m][r] = hv[m][r]; s2[m][r] = hv[m][r]*hv[m][r]; }
      #pragma unroll
      for (int d = 1; d < 16; d <<= 1)
        #pragma unroll
        for (int m = 0; m < 4; ++m)
          #pragma unroll
          for (int r = 0; r < 4; ++r){
            s1[m][r] += __shfl_xor(s1[m][r], d);
            s2[m][r] += __shfl_xor(s2[m][r], d);
          }
      if (lidx == 0){
        #pragma unroll
        for (int m = 0; m < 4; ++m)
          #pragma unroll
          for (int r = 0; r < 4; ++r){
            u.sred[w][m*16 + lgrp*4 + r][0] = s1[m][r];
            u.sred[w][m*16 + lgrp*4 + r][1] = s2[m][r];
          }
      }
    }
    __syncthreads();
    // ph3: finalize LN stats
    if (tid < 64){
      float ss = 0.f, sq = 0.f;
      #pragma unroll
      for (int ww = 0; ww < 8; ++ww){ ss += u.sred[ww][tid][0]; sq += u.sred[ww][tid][1]; }
      float mu = ss * (1.f/128.f);
      float var = sq * (1.f/128.f) - mu*mu;
      u.mus[tid][0] = mu;
      u.mus[tid][1] = __builtin_amdgcn_rsqf(var + 1e-5f);
    }
    __syncthreads();
    // ph4: feat -> hP[2] (overwrites dec_in)
    #pragma unroll
    for (int m = 0; m < 4; ++m)
      #pragma unroll
      for (int r = 0; r < 4; ++r){
        const int row = m*16 + lgrp*4 + r;
        float mu = u.mus[row][0], rs = u.mus[row][1];
        bdin[sidx(row, col)] = f2bf((hv[m][r] - mu)*rs*lngv + lnbv);
      }
    __syncthreads();
    // ph5: heads via MFMA (waves 0..3, M-tile = wave)
    if (w < 4){
      const int arow = w*16 + lidx;
      short8 a[4];
      #pragma unroll
      for (int kt = 0; kt < 4; ++kt)
        a[kt] = *(const short8*)&bdin[sidx(arow, kt*32 + lgrp*8)];
      f32x4 acc = {0.f,0.f,0.f,0.f};
      #pragma unroll
      for (int kt = 0; kt < 4; ++kt)
        acc = __builtin_amdgcn_mfma_f32_16x16x32_bf16(a[kt], whf[kt], acc, 0, 0, 0);
      #pragma unroll
      for (int r = 0; r < 4; ++r){
        const int row = w*16 + lgrp*4 + r;
        float v = acc[r] + bmo;
        if (lidx < 3){
          out[(size_t)(row0 + row)*30 + s*3 + lidx] = v;
          u.prevb[row][lidx] = v;
        } else if (lidx < 6){
          out[(size_t)65536*30 + (size_t)(row0 + row)*30 + s*3 + (lidx - 3)] =
              fminf(fmaxf(v, -6.f), 3.f);
        }
      }
    }
    __syncthreads();
    int tswap = hcur; hcur = hnew; hnew = tswap;
  }
}

extern "C" void kernel_launch(void* const* d_in, const int* in_sizes, int n_in,
                              void* d_out, int out_size, void* d_ws, size_t ws_size,
                              hipStream_t stream)
{
  const float* x    = (const float*)d_in[0];
  const float* Wih0 = (const float*)d_in[1];
  const float* Whh0 = (const float*)d_in[2];
  const float* b0   = (const float*)d_in[3];
  const float* Wih1 = (const float*)d_in[4];
  const float* Whh1 = (const float*)d_in[5];
  const float* b1   = (const float*)d_in[6];
  const float* Wihd = (const float*)d_in[7];
  const float* Whhd = (const float*)d_in[8];
  const float* bd   = (const float*)d_in[9];
  const float* emb  = (const float*)d_in[10];
  const float* Wp   = (const float*)d_in[11];
  const float* bp   = (const float*)d_in[12];
  const float* Wm   = (const float*)d_in[13];
  const float* bm   = (const float*)d_in[14];
  const float* Ws   = (const float*)d_in[15];
  const float* bs   = (const float*)d_in[16];
  const float* lng  = (const float*)d_in[17];
  const float* lnb  = (const float*)d_in[18];

  unsigned short* pkw = (unsigned short*)d_ws;
  float* dbase = (float*)((char*)d_ws + DBASE_OFF);

  pack_w<<<(PK_TOTAL + 255)/256, 256, 0, stream>>>(Wih0, Whh0, Wih1, Whh1,
                                                   Wihd, Whhd, Wm, Ws, pkw);
  prep_decbase<<<10, 128, 0, stream>>>(emb, Wp, bp, dbase);
  traj_main<<<1024, 512, 0, stream>>>(x, pkw, dbase, b0, b1, bd, Wp,
                                      bm, bs, lng, lnb, (float*)d_out);
}

// Round 6
// 2296.049 us; speedup vs baseline: 3.6505x; 1.0340x over previous
//
#include <hip/hip_runtime.h>
#include <stdint.h>

typedef __attribute__((ext_vector_type(8))) short short8;
typedef __attribute__((ext_vector_type(4))) float f32x4;

#define NT 15

// packed bf16 weight fragments in d_ws (element offsets, shorts)
#define SET0 0          // L0: 32 (jt,g) pairs x 5 kt x 512
#define SET1 81920      // L1: 32 pairs x 8 kt x 512
#define SET2 212992     // dec: same shape as L1
#define SET3 344064     // heads [Wm;Ws]: 4 kt x 512
#define PK_TOTAL 346112
#define DBASE_OFF (PK_TOTAL*2)   // byte offset of dbase in ws

__device__ __forceinline__ unsigned short f2bf(float f){
  unsigned int u = __builtin_bit_cast(unsigned int, f);
  u += 0x7fffu + ((u >> 16) & 1u);
  return (unsigned short)(u >> 16);
}
__device__ __forceinline__ float sigf(float x){
  return __builtin_amdgcn_rcpf(1.0f + __expf(-x));
}
__device__ __forceinline__ float tanhf_(float x){
  return 1.0f - 2.0f*__builtin_amdgcn_rcpf(1.0f + __expf(2.0f*x));
}
// XOR-swizzled LDS index (shorts): spreads stride-256B rows across banks.
__device__ __forceinline__ int sidx(int row, int col){
  return row*128 + (col ^ ((row & 7) << 3));
}

// ---------------- prep: pack weights to bf16 MFMA fragments ----------------
// Fragment (n,k): lane holds n = 16-col tile + (lane&15), k = kt*32+(lane>>4)*8+j.
__global__ void pack_w(const float* __restrict__ Wih0, const float* __restrict__ Whh0,
                       const float* __restrict__ Wih1, const float* __restrict__ Whh1,
                       const float* __restrict__ Wihd, const float* __restrict__ Whhd,
                       const float* __restrict__ Wm,  const float* __restrict__ Ws,
                       unsigned short* __restrict__ pk)
{
  int idx = blockIdx.x*256 + threadIdx.x;
  if (idx >= PK_TOTAL) return;
  float v = 0.f;
  if (idx >= SET3){
    int e = idx - SET3;
    int j = e & 7, lane = (e >> 3) & 63, kt = e >> 9;
    int n = lane & 15;
    int k = kt*32 + (lane >> 4)*8 + j;
    if (n < 3) v = Wm[n*128 + k];
    else if (n < 6) v = Ws[(n-3)*128 + k];
  } else {
    int set, e;
    if (idx < SET1){ set = 0; e = idx; }
    else if (idx < SET2){ set = 1; e = idx - SET1; }
    else { set = 2; e = idx - SET2; }
    int j = e & 7, lane = (e >> 3) & 63, rest = e >> 9;
    int nf = (set == 0) ? 5 : 8;
    int kt = rest % nf, pair = rest / nf;
    int g = pair & 3, jt = pair >> 2;
    int n = g*128 + jt*16 + (lane & 15);
    int kk = (lane >> 4)*8 + j;
    if (set == 0){
      if (kt < 4) v = Whh0[n*128 + kt*32 + kk];          // K 0..127 = h0
      else if (kk < 6) v = Wih0[n*6 + kk];               // K-ext tile = x
    } else {
      const float* Wi = (set == 1) ? Wih1 : Wihd;
      const float* Wh = (set == 1) ? Whh1 : Whhd;
      v = (kt < 4) ? Wi[n*128 + kt*32 + kk] : Wh[n*128 + (kt-4)*32 + kk];
    }
  }
  pk[idx] = f2bf(v);
}

// dec_base[s][j] = bp[j] + sum_k emb[s][k]*Wp[j][3+k]
__global__ void prep_decbase(const float* __restrict__ emb, const float* __restrict__ Wp,
                             const float* __restrict__ bp, float* __restrict__ dbase)
{
  int idx = blockIdx.x*128 + threadIdx.x;
  if (idx >= 1280) return;
  int s = idx >> 7, j = idx & 127;
  float acc = bp[j];
  for (int k = 0; k < 128; ++k) acc += emb[s*128 + k] * Wp[j*131 + 3 + k];
  dbase[idx] = acc;
}

// ---------------- main fused kernel ----------------
// 512 thr = 8 waves; block owns 64 rows; wave w owns gate-columns [w*16,w*16+16)
// (all 4 gates). Three rotating 16KB LDS h-buffers. x staged ONCE per block in
// LDS (bf16 [t][row][8]); decoder outputs buffered in LDS and flushed once,
// coalesced, at the end (kills partial-line RMW write amplification).
// Registers (not LDS) cap residency at 2 waves/SIMD, so ~70KB LDS is free.
__global__ __launch_bounds__(512)
void traj_main(const float* __restrict__ x,
               const unsigned short* __restrict__ pk,
               const float* __restrict__ dbase,
               const float* __restrict__ b0g, const float* __restrict__ b1g,
               const float* __restrict__ bdg,
               const float* __restrict__ Wp,
               const float* __restrict__ bm, const float* __restrict__ bs,
               const float* __restrict__ lng, const float* __restrict__ lnb,
               float* __restrict__ out)
{
  __shared__ __align__(16) unsigned short hP[3][64*128];
  __shared__ __align__(16) union {
    unsigned short xs[NT*64*8];               // 15360 B, encoder only
    struct { float om[64][30]; float os[64][30]; } o;   // 15360 B, decoder only
  } u2;
  __shared__ __align__(16) struct {
    float sred[8][64][2];                     // LN partials per wave
    float mus[64][2];                         // mu, rstd per row
    float prevb[64][4];                       // prev-mu broadcast
  } u;

  const int tid  = threadIdx.x;
  const int w    = tid >> 6;
  const int lane = tid & 63;
  const int lidx = lane & 15;
  const int lgrp = lane >> 4;
  const int col  = w*16 + lidx;
  const int row0 = blockIdx.x * 64;

  for (int i = tid; i < 64*128; i += 512){ hP[0][i] = 0; hP[1][i] = 0; }
  // stage ALL of x for this block: [t][row][8] bf16, each element written once
  for (int i = tid; i < NT*64*8; i += 512){
    int k8 = i & 7, rt = i >> 3;
    int r = rt & 63, t = rt >> 6;
    u2.xs[i] = (k8 < 6) ? f2bf(x[(size_t)(row0 + r)*90 + t*6 + k8])
                        : (unsigned short)0;
  }

  float b0v[4], b1v[4];
  #pragma unroll
  for (int g = 0; g < 4; ++g){ b0v[g] = b0g[g*128 + col]; b1v[g] = b1g[g*128 + col]; }

  float c0[4][4], c1[4][4];
  #pragma unroll
  for (int m = 0; m < 4; ++m)
    #pragma unroll
    for (int r = 0; r < 4; ++r){ c0[m][r] = 0.f; c1[m][r] = 0.f; }

  __syncthreads();

  const unsigned short* pw0 = pk + SET0 + (w*4)*(5*512) + lane*8;
  const unsigned short* pw1 = pk + SET1 + (w*4)*(8*512) + lane*8;

  int i0 = 0, i1 = 1, ifr = 2;
  #pragma unroll 1
  for (int t = 0; t < NT; ++t){
    const unsigned short* bh0 = &hP[i0][0];
    const unsigned short* bh1 = &hP[i1][0];
    unsigned short*       bnw = &hP[ifr][0];

    // ---------- layer 0: [h0 | x_t] @ W^T ; read bh0, write bnw ----------
    short8 w0f[4][5];
    #pragma unroll
    for (int g = 0; g < 4; ++g)
      #pragma unroll
      for (int kt = 0; kt < 5; ++kt)
        w0f[g][kt] = *(const short8*)&pw0[(g*5 + kt)*512];
    #pragma unroll
    for (int m = 0; m < 4; ++m){
      const int arow = m*16 + lidx;
      short8 a[5];
      #pragma unroll
      for (int kt = 0; kt < 4; ++kt)
        a[kt] = *(const short8*)&bh0[sidx(arow, kt*32 + lgrp*8)];
      short8 ax = {0,0,0,0,0,0,0,0};
      if (lgrp == 0) ax = *(const short8*)&u2.xs[(t*64 + arow)*8];
      a[4] = ax;
      f32x4 acc[4];
      #pragma unroll
      for (int g = 0; g < 4; ++g){
        f32x4 s = {0.f,0.f,0.f,0.f};
        #pragma unroll
        for (int kt = 0; kt < 5; ++kt)
          s = __builtin_amdgcn_mfma_f32_16x16x32_bf16(a[kt], w0f[g][kt], s, 0, 0, 0);
        acc[g] = s;
      }
      #pragma unroll
      for (int r = 0; r < 4; ++r){
        float iv = sigf(acc[0][r] + b0v[0]);
        float fv = sigf(acc[1][r] + b0v[1]);
        float gv = tanhf_(acc[2][r] + b0v[2]);
        float ov = sigf(acc[3][r] + b0v[3]);
        float c = fv*c0[m][r] + iv*gv;
        c0[m][r] = c;
        bnw[sidx(m*16 + lgrp*4 + r, col)] = f2bf(ov*tanhf_(c));
      }
    }
    __syncthreads();   // bnw (new h0) visible; bh0 now dead

    // ---------- layer 1: [h0_new | h1] @ W^T ; read bnw,bh1, write bh0 ----------
    short8 w1f[4][8];
    #pragma unroll
    for (int g = 0; g < 4; ++g)
      #pragma unroll
      for (int kt = 0; kt < 8; ++kt)
        w1f[g][kt] = *(const short8*)&pw1[(g*8 + kt)*512];
    #pragma unroll
    for (int m = 0; m < 4; ++m){
      const int arow = m*16 + lidx;
      short8 a[8];
      #pragma unroll
      for (int kt = 0; kt < 4; ++kt)
        a[kt] = *(const short8*)&bnw[sidx(arow, kt*32 + lgrp*8)];
      #pragma unroll
      for (int kt = 0; kt < 4; ++kt)
        a[4+kt] = *(const short8*)&bh1[sidx(arow, kt*32 + lgrp*8)];
      f32x4 acc[4];
      #pragma unroll
      for (int g = 0; g < 4; ++g){
        f32x4 s = {0.f,0.f,0.f,0.f};
        #pragma unroll
        for (int kt = 0; kt < 8; ++kt)
          s = __builtin_amdgcn_mfma_f32_16x16x32_bf16(a[kt], w1f[g][kt], s, 0, 0, 0);
        acc[g] = s;
      }
      #pragma unroll
      for (int r = 0; r < 4; ++r){
        float iv = sigf(acc[0][r] + b1v[0]);
        float fv = sigf(acc[1][r] + b1v[1]);
        float gv = tanhf_(acc[2][r] + b1v[2]);
        float ov = sigf(acc[3][r] + b1v[3]);
        float c = fv*c1[m][r] + iv*gv;
        c1[m][r] = c;
        const_cast<unsigned short*>(bh0)[sidx(m*16 + lgrp*4 + r, col)] =
            f2bf(ov*tanhf_(c));
      }
    }
    __syncthreads();   // new h1 (in old-h0 slot) visible
    // rotate roles: h0' = ifr, h1' = i0, free' = i1
    int t0 = i0; i0 = ifr; ifr = i1; i1 = t0;
  }
  // after 15 steps (period 3): (i0,i1,ifr) = (0,1,2); h1 in buffer 1.

  // ===================== decoder =====================
  const unsigned short* pw2 = pk + SET2 + (w*4)*(8*512) + lane*8;
  short8 wdf[4][8];
  #pragma unroll
  for (int g = 0; g < 4; ++g)
    #pragma unroll
    for (int kt = 0; kt < 8; ++kt)
      wdf[g][kt] = *(const short8*)&pw2[(g*8 + kt)*512];
  short8 whf[4];
  {
    const short8 z8 = {0,0,0,0,0,0,0,0};
    #pragma unroll
    for (int kt = 0; kt < 4; ++kt) whf[kt] = z8;
    if (w < 4){
      #pragma unroll
      for (int kt = 0; kt < 4; ++kt)
        whf[kt] = *(const short8*)&pk[SET3 + kt*512 + lane*8];
    }
  }

  const float wpa = Wp[col*131 + 0], wpb = Wp[col*131 + 1], wpc = Wp[col*131 + 2];
  const float lngv = lng[col], lnbv = lnb[col];
  float bdv[4];
  #pragma unroll
  for (int g = 0; g < 4; ++g) bdv[g] = bdg[g*128 + col];
  float bmo = 0.f;
  if (lidx < 3) bmo = bm[lidx];
  else if (lidx < 6) bmo = bs[lidx - 3];

  __syncthreads();   // encoder fully done; u2 switches role xs -> obuf

  if (tid < 192){
    int r = tid / 3, o = tid - r*3;
    u.prevb[r][o] = x[(size_t)(row0 + r)*90 + 14*6 + o];
  }
  __syncthreads();

  int hcur = 1, hnew = 0;          // h1 buffer / target; hP[2] = din & feat
  #pragma unroll 1
  for (int s = 0; s < 10; ++s){
    unsigned short* bdin = &hP[2][0];
    const unsigned short* bh = &hP[hcur][0];
    unsigned short* bhn = &hP[hnew][0];

    // ph1: dec_in = relu(dbase + prev @ Wp3^T) -> hP[2]
    const float dbs = dbase[s*128 + col];
    #pragma unroll
    for (int m = 0; m < 4; ++m)
      #pragma unroll
      for (int r = 0; r < 4; ++r){
        const int row = m*16 + lgrp*4 + r;
        f32x4 pv = *(const f32x4*)&u.prevb[row][0];
        float v = dbs + pv[0]*wpa + pv[1]*wpb + pv[2]*wpc;
        bdin[sidx(row, col)] = f2bf(v > 0.f ? v : 0.f);
      }
    __syncthreads();

    // ph2: LSTM cell; read hP[2]+bh, write bhn
    float hv[4][4];
    #pragma unroll
    for (int m = 0; m < 4; ++m){
      const int arow = m*16 + lidx;
      short8 a[8];
      #pragma unroll
      for (int kt = 0; kt < 4; ++kt)
        a[kt] = *(const short8*)&bdin[sidx(arow, kt*32 + lgrp*8)];
      #pragma unroll
      for (int kt = 0; kt < 4; ++kt)
        a[4+kt] = *(const short8*)&bh[sidx(arow, kt*32 + lgrp*8)];
      f32x4 acc[4];
      #pragma unroll
      for (int g = 0; g < 4; ++g){
        f32x4 sa = {0.f,0.f,0.f,0.f};
        #pragma unroll
        for (int kt = 0; kt < 8; ++kt)
          sa = __builtin_amdgcn_mfma_f32_16x16x32_bf16(a[kt], wdf[g][kt], sa, 0, 0, 0);
        acc[g] = sa;
      }
      #pragma unroll
      for (int r = 0; r < 4; ++r){
        float iv = sigf(acc[0][r] + bdv[0]);
        float fv = sigf(acc[1][r] + bdv[1]);
        float gv = tanhf_(acc[2][r] + bdv[2]);
        float ov = sigf(acc[3][r] + bdv[3]);
        float c = fv*c1[m][r] + iv*gv;
        c1[m][r] = c;
        float h = ov*tanhf_(c);
        hv[m][r] = h;
        bhn[sidx(m*16 + lgrp*4 + r, col)] = f2bf(h);
      }
    }
    // LN partials over this wave's 16 cols (reduce across lidx)
    {
      float s1[4][4], s2[4][4];
      #pragma unroll
      for (int m = 0; m < 4; ++m)
        #pragma unroll
        for (int r = 0; r < 4; ++r){ s1[m][r] = hv[m][r]; s2[m][r] = hv[m][r]*hv[m][r]; }
      #pragma unroll
      for (int d = 1; d < 16; d <<= 1)
        #pragma unroll
        for (int m = 0; m < 4; ++m)
          #pragma unroll
          for (int r = 0; r < 4; ++r){
            s1[m][r] += __shfl_xor(s1[m][r], d);
            s2[m][r] += __shfl_xor(s2[m][r], d);
          }
      if (lidx == 0){
        #pragma unroll
        for (int m = 0; m < 4; ++m)
          #pragma unroll
          for (int r = 0; r < 4; ++r){
            u.sred[w][m*16 + lgrp*4 + r][0] = s1[m][r];
            u.sred[w][m*16 + lgrp*4 + r][1] = s2[m][r];
          }
      }
    }
    __syncthreads();
    // ph3: finalize LN stats
    if (tid < 64){
      float ss = 0.f, sq = 0.f;
      #pragma unroll
      for (int ww = 0; ww < 8; ++ww){ ss += u.sred[ww][tid][0]; sq += u.sred[ww][tid][1]; }
      float mu = ss * (1.f/128.f);
      float var = sq * (1.f/128.f) - mu*mu;
      u.mus[tid][0] = mu;
      u.mus[tid][1] = __builtin_amdgcn_rsqf(var + 1e-5f);
    }
    __syncthreads();
    // ph4: feat -> hP[2] (overwrites dec_in)
    #pragma unroll
    for (int m = 0; m < 4; ++m)
      #pragma unroll
      for (int r = 0; r < 4; ++r){
        const int row = m*16 + lgrp*4 + r;
        float mu = u.mus[row][0], rs = u.mus[row][1];
        bdin[sidx(row, col)] = f2bf((hv[m][r] - mu)*rs*lngv + lnbv);
      }
    __syncthreads();
    // ph5: heads via MFMA (waves 0..3, M-tile = wave); results -> LDS obuf
    if (w < 4){
      const int arow = w*16 + lidx;
      short8 a[4];
      #pragma unroll
      for (int kt = 0; kt < 4; ++kt)
        a[kt] = *(const short8*)&bdin[sidx(arow, kt*32 + lgrp*8)];
      f32x4 acc = {0.f,0.f,0.f,0.f};
      #pragma unroll
      for (int kt = 0; kt < 4; ++kt)
        acc = __builtin_amdgcn_mfma_f32_16x16x32_bf16(a[kt], whf[kt], acc, 0, 0, 0);
      #pragma unroll
      for (int r = 0; r < 4; ++r){
        const int row = w*16 + lgrp*4 + r;
        float v = acc[r] + bmo;
        if (lidx < 3){
          u2.o.om[row][s*3 + lidx] = v;
          u.prevb[row][lidx] = v;
        } else if (lidx < 6){
          u2.o.os[row][s*3 + (lidx - 3)] = fminf(fmaxf(v, -6.f), 3.f);
        }
      }
    }
    __syncthreads();
    int tswap = hcur; hcur = hnew; hnew = tswap;
  }

  // ---- single coalesced output flush ----
  for (int i = tid; i < 1920; i += 512){
    int r = i / 30, cx = i - r*30;
    out[(size_t)(row0 + r)*30 + cx] = u2.o.om[r][cx];
    out[(size_t)65536*30 + (size_t)(row0 + r)*30 + cx] = u2.o.os[r][cx];
  }
}

extern "C" void kernel_launch(void* const* d_in, const int* in_sizes, int n_in,
                              void* d_out, int out_size, void* d_ws, size_t ws_size,
                              hipStream_t stream)
{
  const float* x    = (const float*)d_in[0];
  const float* Wih0 = (const float*)d_in[1];
  const float* Whh0 = (const float*)d_in[2];
  const float* b0   = (const float*)d_in[3];
  const float* Wih1 = (const float*)d_in[4];
  const float* Whh1 = (const float*)d_in[5];
  const float* b1   = (const float*)d_in[6];
  const float* Wihd = (const float*)d_in[7];
  const float* Whhd = (const float*)d_in[8];
  const float* bd   = (const float*)d_in[9];
  const float* emb  = (const float*)d_in[10];
  const float* Wp   = (const float*)d_in[11];
  const float* bp   = (const float*)d_in[12];
  const float* Wm   = (const float*)d_in[13];
  const float* bm   = (const float*)d_in[14];
  const float* Ws   = (const float*)d_in[15];
  const float* bs   = (const float*)d_in[16];
  const float* lng  = (const float*)d_in[17];
  const float* lnb  = (const float*)d_in[18];

  unsigned short* pkw = (unsigned short*)d_ws;
  float* dbase = (float*)((char*)d_ws + DBASE_OFF);

  pack_w<<<(PK_TOTAL + 255)/256, 256, 0, stream>>>(Wih0, Whh0, Wih1, Whh1,
                                                   Wihd, Whhd, Wm, Ws, pkw);
  prep_decbase<<<10, 128, 0, stream>>>(emb, Wp, bp, dbase);
  traj_main<<<1024, 512, 0, stream>>>(x, pkw, dbase, b0, b1, bd, Wp,
                                      bm, bs, lng, lnb, (float*)d_out);
}

// Round 7
// 2077.234 us; speedup vs baseline: 4.0350x; 1.1053x over previous
//
#include <hip/hip_runtime.h>
#include <stdint.h>

typedef __attribute__((ext_vector_type(8))) short short8;
typedef __attribute__((ext_vector_type(4))) float f32x4;

#define NT 15

// packed bf16 weight fragments in d_ws (element offsets, shorts)
#define SET0 0          // L0: 32 (jt,g) pairs x 5 kt x 512
#define SET1 81920      // L1: 32 pairs x 8 kt x 512
#define SET2 212992     // dec: same shape as L1
#define SET3 344064     // heads (unused by main now, kept for layout stability)
#define PK_TOTAL 346112
#define DD_OFF (PK_TOTAL*2)   // byte offset of dec-const block in ws:
                              // dbase[1280] | hw[768] | hb[6] | hc[6]  (floats)

__device__ __forceinline__ unsigned short f2bf(float f){
  unsigned int u = __builtin_bit_cast(unsigned int, f);
  u += 0x7fffu + ((u >> 16) & 1u);
  return (unsigned short)(u >> 16);
}
__device__ __forceinline__ float sigf(float x){
  return __builtin_amdgcn_rcpf(1.0f + __expf(-x));
}
__device__ __forceinline__ float tanhf_(float x){
  return 1.0f - 2.0f*__builtin_amdgcn_rcpf(1.0f + __expf(2.0f*x));
}
// XOR-swizzled LDS index (shorts): spreads stride-256B rows across banks.
__device__ __forceinline__ int sidx(int row, int col){
  return row*128 + (col ^ ((row & 7) << 3));
}
// Raw workgroup barrier: LDS visibility only (no vmcnt drain -> global loads
// issued before the barrier stay in flight across it).
__device__ __forceinline__ void BAR(){
  asm volatile("s_waitcnt lgkmcnt(0)" ::: "memory");
  __builtin_amdgcn_s_barrier();
}

// ---------------- prep: pack weights to bf16 MFMA fragments ----------------
__global__ void pack_w(const float* __restrict__ Wih0, const float* __restrict__ Whh0,
                       const float* __restrict__ Wih1, const float* __restrict__ Whh1,
                       const float* __restrict__ Wihd, const float* __restrict__ Whhd,
                       const float* __restrict__ Wm,  const float* __restrict__ Ws,
                       unsigned short* __restrict__ pk)
{
  int idx = blockIdx.x*256 + threadIdx.x;
  if (idx >= PK_TOTAL) return;
  float v = 0.f;
  if (idx >= SET3){
    int e = idx - SET3;
    int j = e & 7, lane = (e >> 3) & 63, kt = e >> 9;
    int n = lane & 15;
    int k = kt*32 + (lane >> 4)*8 + j;
    if (n < 3) v = Wm[n*128 + k];
    else if (n < 6) v = Ws[(n-3)*128 + k];
  } else {
    int set, e;
    if (idx < SET1){ set = 0; e = idx; }
    else if (idx < SET2){ set = 1; e = idx - SET1; }
    else { set = 2; e = idx - SET2; }
    int j = e & 7, lane = (e >> 3) & 63, rest = e >> 9;
    int nf = (set == 0) ? 5 : 8;
    int kt = rest % nf, pair = rest / nf;
    int g = pair & 3, jt = pair >> 2;
    int n = g*128 + jt*16 + (lane & 15);
    int kk = (lane >> 4)*8 + j;
    if (set == 0){
      if (kt < 4) v = Whh0[n*128 + kt*32 + kk];          // K 0..127 = h0
      else if (kk < 6) v = Wih0[n*6 + kk];               // K-ext tile = x
    } else {
      const float* Wi = (set == 1) ? Wih1 : Wihd;
      const float* Wh = (set == 1) ? Whh1 : Whhd;
      v = (kt < 4) ? Wi[n*128 + kt*32 + kk] : Wh[n*128 + (kt-4)*32 + kk];
    }
  }
  pk[idx] = f2bf(v);
}

// decoder constants:
// dbase[s][j] = bp[j] + sum_k emb[s][k]*Wp[j][3+k]
// hw[o][j]    = W[o][j]*ln_g[j]        (W = Wm rows 0..2, Ws rows 3..5)
// hb[o]       = sum_j hw[o][j]
// hc[o]       = bias_o + sum_j W[o][j]*ln_b[j]
__global__ void prep_dec(const float* __restrict__ emb, const float* __restrict__ Wp,
                         const float* __restrict__ bp,
                         const float* __restrict__ Wm, const float* __restrict__ Ws,
                         const float* __restrict__ bm, const float* __restrict__ bs,
                         const float* __restrict__ lng, const float* __restrict__ lnb,
                         float* __restrict__ dd)
{
  int idx = blockIdx.x*128 + threadIdx.x;
  if (idx < 1280){
    int s = idx >> 7, j = idx & 127;
    float acc = bp[j];
    for (int k = 0; k < 128; ++k) acc += emb[s*128 + k] * Wp[j*131 + 3 + k];
    dd[idx] = acc;
  } else if (idx < 2048){
    int e = idx - 1280; int o = e >> 7, j = e & 127;
    const float* W = (o < 3) ? (Wm + o*128) : (Ws + (o-3)*128);
    dd[idx] = W[j] * lng[j];
  } else if (idx < 2054){
    int o = idx - 2048;
    const float* W = (o < 3) ? (Wm + o*128) : (Ws + (o-3)*128);
    float a = 0.f;
    for (int k = 0; k < 128; ++k) a += W[k]*lng[k];
    dd[idx] = a;
  } else if (idx < 2060){
    int o = idx - 2054;
    const float* W = (o < 3) ? (Wm + o*128) : (Ws + (o-3)*128);
    float a = (o < 3) ? bm[o] : bs[o-3];
    for (int k = 0; k < 128; ++k) a += W[k]*lnb[k];
    dd[idx] = a;
  }
}

// ---------------- main fused kernel ----------------
// 512 thr = 8 waves; block owns 64 rows; wave w owns h-cols [w*16,w*16+16)
// across all 4 gates. kt-outer MFMA loops keep live regs ~205 (no spills).
// Decoder: LN+heads folded into cell phase via precomputed hw/hb/hc -> 3
// barriers/step. Raw lgkm-only barriers in hot loops.
__global__ __launch_bounds__(512)
void traj_main(const float* __restrict__ x,
               const unsigned short* __restrict__ pk,
               const float* __restrict__ dd,
               const float* __restrict__ b0g, const float* __restrict__ b1g,
               const float* __restrict__ bdg,
               const float* __restrict__ Wp,
               float* __restrict__ out)
{
  __shared__ __align__(16) unsigned short hP[3][64*128];
  __shared__ __align__(16) union {
    unsigned short xs[NT*64*8];                        // 15360 B (encoder)
    struct { float om[64][30]; float os[64][30]; } o;  // 15360 B (decoder)
  } u2;
  __shared__ __align__(16) struct {
    float sred[8][64][8];    // per-wave partials: s1,s2,A0..A5
    float prevb[64][4];
  } u;

  const int tid  = threadIdx.x;
  const int w    = tid >> 6;
  const int lane = tid & 63;
  const int lidx = lane & 15;
  const int lgrp = lane >> 4;
  const int col  = w*16 + lidx;
  const int row0 = blockIdx.x * 64;

  for (int i = tid; i < 64*128; i += 512){ hP[0][i] = 0; hP[1][i] = 0; }
  for (int i = tid; i < NT*64*8; i += 512){
    int k8 = i & 7, rt = i >> 3;
    int r = rt & 63, t = rt >> 6;
    u2.xs[i] = (k8 < 6) ? f2bf(x[(size_t)(row0 + r)*90 + t*6 + k8])
                        : (unsigned short)0;
  }

  float b0v[4], b1v[4];
  #pragma unroll
  for (int g = 0; g < 4; ++g){ b0v[g] = b0g[g*128 + col]; b1v[g] = b1g[g*128 + col]; }

  float c0[4][4], c1[4][4];
  #pragma unroll
  for (int m = 0; m < 4; ++m)
    #pragma unroll
    for (int r = 0; r < 4; ++r){ c0[m][r] = 0.f; c1[m][r] = 0.f; }

  __syncthreads();

  const unsigned short* pw0 = pk + SET0 + (w*4)*(5*512) + lane*8;
  const unsigned short* pw1 = pk + SET1 + (w*4)*(8*512) + lane*8;
  const unsigned short* pw2 = pk + SET2 + (w*4)*(8*512) + lane*8;
  const short8 z8 = {0,0,0,0,0,0,0,0};

  int i0 = 0, i1 = 1, ifr = 2;
  #pragma unroll 1
  for (int t = 0; t < NT; ++t){
    const unsigned short* bh0 = &hP[i0][0];
    const unsigned short* bh1 = &hP[i1][0];
    unsigned short*       bnw = &hP[ifr][0];

    // ---------- layer 0: [h0 | x_t] @ W^T ; read bh0, write bnw ----------
    {
      f32x4 acc[4][4];
      #pragma unroll
      for (int m = 0; m < 4; ++m)
        #pragma unroll
        for (int g = 0; g < 4; ++g)
          acc[m][g] = (f32x4){b0v[g], b0v[g], b0v[g], b0v[g]};
      #pragma unroll
      for (int kt = 0; kt < 5; ++kt){
        short8 am[4];
        #pragma unroll
        for (int m = 0; m < 4; ++m){
          if (kt < 4)
            am[m] = *(const short8*)&bh0[sidx(m*16 + lidx, kt*32 + lgrp*8)];
          else
            am[m] = (lgrp == 0) ? *(const short8*)&u2.xs[(t*64 + m*16 + lidx)*8] : z8;
        }
        #pragma unroll
        for (int g = 0; g < 4; ++g){
          short8 wv = *(const short8*)&pw0[(g*5 + kt)*512];
          #pragma unroll
          for (int m = 0; m < 4; ++m)
            acc[m][g] = __builtin_amdgcn_mfma_f32_16x16x32_bf16(am[m], wv, acc[m][g], 0, 0, 0);
        }
      }
      #pragma unroll
      for (int m = 0; m < 4; ++m)
        #pragma unroll
        for (int r = 0; r < 4; ++r){
          float iv = sigf(acc[m][0][r]);
          float fv = sigf(acc[m][1][r]);
          float gv = tanhf_(acc[m][2][r]);
          float ov = sigf(acc[m][3][r]);
          float c = fv*c0[m][r] + iv*gv;
          c0[m][r] = c;
          bnw[sidx(m*16 + lgrp*4 + r, col)] = f2bf(ov*tanhf_(c));
        }
    }
    BAR();   // bnw (new h0) visible; bh0 now dead

    // ---------- layer 1: [h0_new | h1] @ W^T ; read bnw,bh1, write bh0 ----------
    {
      f32x4 acc[4][4];
      #pragma unroll
      for (int m = 0; m < 4; ++m)
        #pragma unroll
        for (int g = 0; g < 4; ++g)
          acc[m][g] = (f32x4){b1v[g], b1v[g], b1v[g], b1v[g]};
      #pragma unroll
      for (int kt = 0; kt < 8; ++kt){
        short8 am[4];
        #pragma unroll
        for (int m = 0; m < 4; ++m){
          if (kt < 4)
            am[m] = *(const short8*)&bnw[sidx(m*16 + lidx, kt*32 + lgrp*8)];
          else
            am[m] = *(const short8*)&bh1[sidx(m*16 + lidx, (kt-4)*32 + lgrp*8)];
        }
        #pragma unroll
        for (int g = 0; g < 4; ++g){
          short8 wv = *(const short8*)&pw1[(g*8 + kt)*512];
          #pragma unroll
          for (int m = 0; m < 4; ++m)
            acc[m][g] = __builtin_amdgcn_mfma_f32_16x16x32_bf16(am[m], wv, acc[m][g], 0, 0, 0);
        }
      }
      unsigned short* bwr = const_cast<unsigned short*>(bh0);
      #pragma unroll
      for (int m = 0; m < 4; ++m)
        #pragma unroll
        for (int r = 0; r < 4; ++r){
          float iv = sigf(acc[m][0][r]);
          float fv = sigf(acc[m][1][r]);
          float gv = tanhf_(acc[m][2][r]);
          float ov = sigf(acc[m][3][r]);
          float c = fv*c1[m][r] + iv*gv;
          c1[m][r] = c;
          bwr[sidx(m*16 + lgrp*4 + r, col)] = f2bf(ov*tanhf_(c));
        }
    }
    BAR();   // new h1 (in old-h0 slot) visible
    int t0 = i0; i0 = ifr; ifr = i1; i1 = t0;
  }
  // after 15 steps (period 3): h1 lives in hP[1].

  // ===================== decoder =====================
  const float* dbase = dd;
  const float* hwp   = dd + 1280;
  const float* hbp   = dd + 2048;
  const float* hcp   = dd + 2054;

  const float wpa = Wp[col*131 + 0], wpb = Wp[col*131 + 1], wpc = Wp[col*131 + 2];
  float bdv[4];
  #pragma unroll
  for (int g = 0; g < 4; ++g) bdv[g] = bdg[g*128 + col];
  float hwv[6], hbv[6], hcv[6];
  #pragma unroll
  for (int o = 0; o < 6; ++o){
    hwv[o] = hwp[o*128 + col];
    hbv[o] = hbp[o];
    hcv[o] = hcp[o];
  }

  if (tid < 192){
    int r = tid / 3, o = tid - r*3;
    u.prevb[r][o] = x[(size_t)(row0 + r)*90 + 14*6 + o];
  }
  __syncthreads();   // also separates u2 role switch xs -> obuf

  int hcur = 1, hnew = 0;          // h1 buffer / target; hP[2] = dec_in
  #pragma unroll 1
  for (int s = 0; s < 10; ++s){
    unsigned short* bdin = &hP[2][0];
    const unsigned short* bh = &hP[hcur][0];
    unsigned short* bhn = &hP[hnew][0];

    // ph1: dec_in = relu(dbase + prev @ Wp3^T) -> hP[2]
    const float dbs = dbase[s*128 + col];
    #pragma unroll
    for (int m = 0; m < 4; ++m)
      #pragma unroll
      for (int r = 0; r < 4; ++r){
        const int row = m*16 + lgrp*4 + r;
        f32x4 pv = *(const f32x4*)&u.prevb[row][0];
        float v = dbs + pv[0]*wpa + pv[1]*wpb + pv[2]*wpc;
        bdin[sidx(row, col)] = f2bf(v > 0.f ? v : 0.f);
      }
    BAR();

    // ph2: LSTM cell (kt-outer) + fused LN/head partials
    {
      f32x4 acc[4][4];
      #pragma unroll
      for (int m = 0; m < 4; ++m)
        #pragma unroll
        for (int g = 0; g < 4; ++g)
          acc[m][g] = (f32x4){bdv[g], bdv[g], bdv[g], bdv[g]};
      #pragma unroll
      for (int kt = 0; kt < 8; ++kt){
        short8 am[4];
        #pragma unroll
        for (int m = 0; m < 4; ++m){
          if (kt < 4)
            am[m] = *(const short8*)&bdin[sidx(m*16 + lidx, kt*32 + lgrp*8)];
          else
            am[m] = *(const short8*)&bh[sidx(m*16 + lidx, (kt-4)*32 + lgrp*8)];
        }
        #pragma unroll
        for (int g = 0; g < 4; ++g){
          short8 wv = *(const short8*)&pw2[(g*8 + kt)*512];
          #pragma unroll
          for (int m = 0; m < 4; ++m)
            acc[m][g] = __builtin_amdgcn_mfma_f32_16x16x32_bf16(am[m], wv, acc[m][g], 0, 0, 0);
        }
      }
      #pragma unroll
      for (int m = 0; m < 4; ++m)
        #pragma unroll
        for (int r = 0; r < 4; ++r){
          float iv = sigf(acc[m][0][r]);
          float fv = sigf(acc[m][1][r]);
          float gv = tanhf_(acc[m][2][r]);
          float ov = sigf(acc[m][3][r]);
          float c = fv*c1[m][r] + iv*gv;
          c1[m][r] = c;
          float h = ov*tanhf_(c);
          const int row = m*16 + lgrp*4 + r;
          bhn[sidx(row, col)] = f2bf(h);
          float vals[8];
          vals[0] = h; vals[1] = h*h;
          #pragma unroll
          for (int o = 0; o < 6; ++o) vals[2+o] = h*hwv[o];
          #pragma unroll
          for (int d = 1; d < 16; d <<= 1)
            #pragma unroll
            for (int k = 0; k < 8; ++k)
              vals[k] += __shfl_xor(vals[k], d);
          if (lidx == 0){
            *(f32x4*)&u.sred[w][row][0] = (f32x4){vals[0], vals[1], vals[2], vals[3]};
            *(f32x4*)&u.sred[w][row][4] = (f32x4){vals[4], vals[5], vals[6], vals[7]};
          }
        }
    }
    BAR();

    // ph3: per-row finalize (stats + both heads), one thread per row
    if (tid < 64){
      float s1 = 0.f, s2 = 0.f;
      float A[6] = {0.f, 0.f, 0.f, 0.f, 0.f, 0.f};
      #pragma unroll
      for (int ww = 0; ww < 8; ++ww){
        f32x4 v0 = *(const f32x4*)&u.sred[ww][tid][0];
        f32x4 v1 = *(const f32x4*)&u.sred[ww][tid][4];
        s1 += v0[0]; s2 += v0[1];
        A[0] += v0[2]; A[1] += v0[3];
        A[2] += v1[0]; A[3] += v1[1]; A[4] += v1[2]; A[5] += v1[3];
      }
      float mu = s1 * (1.f/128.f);
      float var = s2 * (1.f/128.f) - mu*mu;
      float rs = __builtin_amdgcn_rsqf(var + 1e-5f);
      #pragma unroll
      for (int o = 0; o < 3; ++o){
        float v = rs*(A[o] - mu*hbv[o]) + hcv[o];
        u2.o.om[tid][s*3 + o] = v;
        u.prevb[tid][o] = v;
      }
      #pragma unroll
      for (int o = 3; o < 6; ++o){
        float v = rs*(A[o] - mu*hbv[o]) + hcv[o];
        u2.o.os[tid][s*3 + (o-3)] = fminf(fmaxf(v, -6.f), 3.f);
      }
    }
    BAR();
    int tswap = hcur; hcur = hnew; hnew = tswap;
  }

  // ---- single coalesced output flush ----
  for (int i = tid; i < 1920; i += 512){
    int r = i / 30, cx = i - r*30;
    out[(size_t)(row0 + r)*30 + cx] = u2.o.om[r][cx];
    out[(size_t)65536*30 + (size_t)(row0 + r)*30 + cx] = u2.o.os[r][cx];
  }
}

extern "C" void kernel_launch(void* const* d_in, const int* in_sizes, int n_in,
                              void* d_out, int out_size, void* d_ws, size_t ws_size,
                              hipStream_t stream)
{
  const float* x    = (const float*)d_in[0];
  const float* Wih0 = (const float*)d_in[1];
  const float* Whh0 = (const float*)d_in[2];
  const float* b0   = (const float*)d_in[3];
  const float* Wih1 = (const float*)d_in[4];
  const float* Whh1 = (const float*)d_in[5];
  const float* b1   = (const float*)d_in[6];
  const float* Wihd = (const float*)d_in[7];
  const float* Whhd = (const float*)d_in[8];
  const float* bd   = (const float*)d_in[9];
  const float* emb  = (const float*)d_in[10];
  const float* Wp   = (const float*)d_in[11];
  const float* bp   = (const float*)d_in[12];
  const float* Wm   = (const float*)d_in[13];
  const float* bm   = (const float*)d_in[14];
  const float* Ws   = (const float*)d_in[15];
  const float* bs   = (const float*)d_in[16];
  const float* lng  = (const float*)d_in[17];
  const float* lnb  = (const float*)d_in[18];

  unsigned short* pkw = (unsigned short*)d_ws;
  float* dd = (float*)((char*)d_ws + DD_OFF);

  pack_w<<<(PK_TOTAL + 255)/256, 256, 0, stream>>>(Wih0, Whh0, Wih1, Whh1,
                                                   Wihd, Whhd, Wm, Ws, pkw);
  prep_dec<<<17, 128, 0, stream>>>(emb, Wp, bp, Wm, Ws, bm, bs, lng, lnb, dd);
  traj_main<<<1024, 512, 0, stream>>>(x, pkw, dd, b0, b1, bd, Wp, (float*)d_out);
}

// Round 8
// 2074.199 us; speedup vs baseline: 4.0409x; 1.0015x over previous
//
#include <hip/hip_runtime.h>
#include <stdint.h>

typedef __attribute__((ext_vector_type(8))) short short8;
typedef __attribute__((ext_vector_type(4))) float f32x4;

#define NT 15

// packed bf16 weight fragments in d_ws (element offsets, shorts)
#define SET0 0          // L0: 32 (jt,g) pairs x 5 kt x 512
#define SET1 81920      // L1: 32 pairs x 8 kt x 512
#define SET2 212992     // dec: same shape as L1
#define SET3 344064     // heads (unused by main now, kept for layout stability)
#define PK_TOTAL 346112
#define DD_OFF (PK_TOTAL*2)   // byte offset of dec-const block in ws:
                              // dbase[1280] | hw[768] | hb[6] | hc[6]  (floats)

__device__ __forceinline__ unsigned short f2bf(float f){
  unsigned int u = __builtin_bit_cast(unsigned int, f);
  u += 0x7fffu + ((u >> 16) & 1u);
  return (unsigned short)(u >> 16);
}
__device__ __forceinline__ float sigf(float x){
  return __builtin_amdgcn_rcpf(1.0f + __expf(-x));
}
__device__ __forceinline__ float tanhf_(float x){
  return 1.0f - 2.0f*__builtin_amdgcn_rcpf(1.0f + __expf(2.0f*x));
}
// XOR-swizzled LDS index (shorts): spreads stride-256B rows across banks.
__device__ __forceinline__ int sidx(int row, int col){
  return row*128 + (col ^ ((row & 7) << 3));
}
// Raw workgroup barrier: LDS visibility only (no vmcnt drain -> global loads
// issued before the barrier stay in flight across it).
__device__ __forceinline__ void BAR(){
  asm volatile("s_waitcnt lgkmcnt(0)" ::: "memory");
  __builtin_amdgcn_s_barrier();
}

// ---------------- prep: pack weights to bf16 MFMA fragments ----------------
__global__ void pack_w(const float* __restrict__ Wih0, const float* __restrict__ Whh0,
                       const float* __restrict__ Wih1, const float* __restrict__ Whh1,
                       const float* __restrict__ Wihd, const float* __restrict__ Whhd,
                       const float* __restrict__ Wm,  const float* __restrict__ Ws,
                       unsigned short* __restrict__ pk)
{
  int idx = blockIdx.x*256 + threadIdx.x;
  if (idx >= PK_TOTAL) return;
  float v = 0.f;
  if (idx >= SET3){
    int e = idx - SET3;
    int j = e & 7, lane = (e >> 3) & 63, kt = e >> 9;
    int n = lane & 15;
    int k = kt*32 + (lane >> 4)*8 + j;
    if (n < 3) v = Wm[n*128 + k];
    else if (n < 6) v = Ws[(n-3)*128 + k];
  } else {
    int set, e;
    if (idx < SET1){ set = 0; e = idx; }
    else if (idx < SET2){ set = 1; e = idx - SET1; }
    else { set = 2; e = idx - SET2; }
    int j = e & 7, lane = (e >> 3) & 63, rest = e >> 9;
    int nf = (set == 0) ? 5 : 8;
    int kt = rest % nf, pair = rest / nf;
    int g = pair & 3, jt = pair >> 2;
    int n = g*128 + jt*16 + (lane & 15);
    int kk = (lane >> 4)*8 + j;
    if (set == 0){
      if (kt < 4) v = Whh0[n*128 + kt*32 + kk];          // K 0..127 = h0
      else if (kk < 6) v = Wih0[n*6 + kk];               // K-ext tile = x
    } else {
      const float* Wi = (set == 1) ? Wih1 : Wihd;
      const float* Wh = (set == 1) ? Whh1 : Whhd;
      v = (kt < 4) ? Wi[n*128 + kt*32 + kk] : Wh[n*128 + (kt-4)*32 + kk];
    }
  }
  pk[idx] = f2bf(v);
}

// decoder constants:
// dbase[s][j] = bp[j] + sum_k emb[s][k]*Wp[j][3+k]
// hw[o][j]    = W[o][j]*ln_g[j]        (W = Wm rows 0..2, Ws rows 3..5)
// hb[o]       = sum_j hw[o][j]
// hc[o]       = bias_o + sum_j W[o][j]*ln_b[j]
__global__ void prep_dec(const float* __restrict__ emb, const float* __restrict__ Wp,
                         const float* __restrict__ bp,
                         const float* __restrict__ Wm, const float* __restrict__ Ws,
                         const float* __restrict__ bm, const float* __restrict__ bs,
                         const float* __restrict__ lng, const float* __restrict__ lnb,
                         float* __restrict__ dd)
{
  int idx = blockIdx.x*128 + threadIdx.x;
  if (idx < 1280){
    int s = idx >> 7, j = idx & 127;
    float acc = bp[j];
    for (int k = 0; k < 128; ++k) acc += emb[s*128 + k] * Wp[j*131 + 3 + k];
    dd[idx] = acc;
  } else if (idx < 2048){
    int e = idx - 1280; int o = e >> 7, j = e & 127;
    const float* W = (o < 3) ? (Wm + o*128) : (Ws + (o-3)*128);
    dd[idx] = W[j] * lng[j];
  } else if (idx < 2054){
    int o = idx - 2048;
    const float* W = (o < 3) ? (Wm + o*128) : (Ws + (o-3)*128);
    float a = 0.f;
    for (int k = 0; k < 128; ++k) a += W[k]*lng[k];
    dd[idx] = a;
  } else if (idx < 2060){
    int o = idx - 2054;
    const float* W = (o < 3) ? (Wm + o*128) : (Ws + (o-3)*128);
    float a = (o < 3) ? bm[o] : bs[o-3];
    for (int k = 0; k < 128; ++k) a += W[k]*lnb[k];
    dd[idx] = a;
  }
}

// ---------------- main fused kernel ----------------
// 512 thr = 8 waves; block owns 64 rows; wave w owns h-cols [w*16,w*16+16)
// across all 4 gates. kt-outer MFMA loops; true live set ~205 regs.
// __launch_bounds__(512, 2): min 2 waves/EU -> VGPR cap 256 (not the default
// 128) -> NO SPILLS. r1-r7 all spilled (WRITE_SIZE 290-500MB vs 16MB
// compulsory); the scratch stream thrashed L2 and put weight re-fetch from
// HBM on the phase critical path. Occupancy is 1 block/CU either way (LDS).
__global__ __launch_bounds__(512, 2)
void traj_main(const float* __restrict__ x,
               const unsigned short* __restrict__ pk,
               const float* __restrict__ dd,
               const float* __restrict__ b0g, const float* __restrict__ b1g,
               const float* __restrict__ bdg,
               const float* __restrict__ Wp,
               float* __restrict__ out)
{
  __shared__ __align__(16) unsigned short hP[3][64*128];
  __shared__ __align__(16) union {
    unsigned short xs[NT*64*8];                        // 15360 B (encoder)
    struct { float om[64][30]; float os[64][30]; } o;  // 15360 B (decoder)
  } u2;
  __shared__ __align__(16) struct {
    float sred[8][64][8];    // per-wave partials: s1,s2,A0..A5
    float prevb[64][4];
  } u;

  const int tid  = threadIdx.x;
  const int w    = tid >> 6;
  const int lane = tid & 63;
  const int lidx = lane & 15;
  const int lgrp = lane >> 4;
  const int col  = w*16 + lidx;
  const int row0 = blockIdx.x * 64;

  for (int i = tid; i < 64*128; i += 512){ hP[0][i] = 0; hP[1][i] = 0; }
  for (int i = tid; i < NT*64*8; i += 512){
    int k8 = i & 7, rt = i >> 3;
    int r = rt & 63, t = rt >> 6;
    u2.xs[i] = (k8 < 6) ? f2bf(x[(size_t)(row0 + r)*90 + t*6 + k8])
                        : (unsigned short)0;
  }

  float b0v[4], b1v[4];
  #pragma unroll
  for (int g = 0; g < 4; ++g){ b0v[g] = b0g[g*128 + col]; b1v[g] = b1g[g*128 + col]; }

  float c0[4][4], c1[4][4];
  #pragma unroll
  for (int m = 0; m < 4; ++m)
    #pragma unroll
    for (int r = 0; r < 4; ++r){ c0[m][r] = 0.f; c1[m][r] = 0.f; }

  __syncthreads();

  const unsigned short* pw0 = pk + SET0 + (w*4)*(5*512) + lane*8;
  const unsigned short* pw1 = pk + SET1 + (w*4)*(8*512) + lane*8;
  const unsigned short* pw2 = pk + SET2 + (w*4)*(8*512) + lane*8;
  const short8 z8 = {0,0,0,0,0,0,0,0};

  int i0 = 0, i1 = 1, ifr = 2;
  #pragma unroll 1
  for (int t = 0; t < NT; ++t){
    const unsigned short* bh0 = &hP[i0][0];
    const unsigned short* bh1 = &hP[i1][0];
    unsigned short*       bnw = &hP[ifr][0];

    // ---------- layer 0: [h0 | x_t] @ W^T ; read bh0, write bnw ----------
    {
      f32x4 acc[4][4];
      #pragma unroll
      for (int m = 0; m < 4; ++m)
        #pragma unroll
        for (int g = 0; g < 4; ++g)
          acc[m][g] = (f32x4){b0v[g], b0v[g], b0v[g], b0v[g]};
      #pragma unroll
      for (int kt = 0; kt < 5; ++kt){
        short8 am[4];
        #pragma unroll
        for (int m = 0; m < 4; ++m){
          if (kt < 4)
            am[m] = *(const short8*)&bh0[sidx(m*16 + lidx, kt*32 + lgrp*8)];
          else
            am[m] = (lgrp == 0) ? *(const short8*)&u2.xs[(t*64 + m*16 + lidx)*8] : z8;
        }
        #pragma unroll
        for (int g = 0; g < 4; ++g){
          short8 wv = *(const short8*)&pw0[(g*5 + kt)*512];
          #pragma unroll
          for (int m = 0; m < 4; ++m)
            acc[m][g] = __builtin_amdgcn_mfma_f32_16x16x32_bf16(am[m], wv, acc[m][g], 0, 0, 0);
        }
      }
      #pragma unroll
      for (int m = 0; m < 4; ++m)
        #pragma unroll
        for (int r = 0; r < 4; ++r){
          float iv = sigf(acc[m][0][r]);
          float fv = sigf(acc[m][1][r]);
          float gv = tanhf_(acc[m][2][r]);
          float ov = sigf(acc[m][3][r]);
          float c = fv*c0[m][r] + iv*gv;
          c0[m][r] = c;
          bnw[sidx(m*16 + lgrp*4 + r, col)] = f2bf(ov*tanhf_(c));
        }
    }
    BAR();   // bnw (new h0) visible; bh0 now dead

    // ---------- layer 1: [h0_new | h1] @ W^T ; read bnw,bh1, write bh0 ----------
    {
      f32x4 acc[4][4];
      #pragma unroll
      for (int m = 0; m < 4; ++m)
        #pragma unroll
        for (int g = 0; g < 4; ++g)
          acc[m][g] = (f32x4){b1v[g], b1v[g], b1v[g], b1v[g]};
      #pragma unroll
      for (int kt = 0; kt < 8; ++kt){
        short8 am[4];
        #pragma unroll
        for (int m = 0; m < 4; ++m){
          if (kt < 4)
            am[m] = *(const short8*)&bnw[sidx(m*16 + lidx, kt*32 + lgrp*8)];
          else
            am[m] = *(const short8*)&bh1[sidx(m*16 + lidx, (kt-4)*32 + lgrp*8)];
        }
        #pragma unroll
        for (int g = 0; g < 4; ++g){
          short8 wv = *(const short8*)&pw1[(g*8 + kt)*512];
          #pragma unroll
          for (int m = 0; m < 4; ++m)
            acc[m][g] = __builtin_amdgcn_mfma_f32_16x16x32_bf16(am[m], wv, acc[m][g], 0, 0, 0);
        }
      }
      unsigned short* bwr = const_cast<unsigned short*>(bh0);
      #pragma unroll
      for (int m = 0; m < 4; ++m)
        #pragma unroll
        for (int r = 0; r < 4; ++r){
          float iv = sigf(acc[m][0][r]);
          float fv = sigf(acc[m][1][r]);
          float gv = tanhf_(acc[m][2][r]);
          float ov = sigf(acc[m][3][r]);
          float c = fv*c1[m][r] + iv*gv;
          c1[m][r] = c;
          bwr[sidx(m*16 + lgrp*4 + r, col)] = f2bf(ov*tanhf_(c));
        }
    }
    BAR();   // new h1 (in old-h0 slot) visible
    int t0 = i0; i0 = ifr; ifr = i1; i1 = t0;
  }
  // after 15 steps (period 3): h1 lives in hP[1].

  // ===================== decoder =====================
  const float* dbase = dd;
  const float* hwp   = dd + 1280;
  const float* hbp   = dd + 2048;
  const float* hcp   = dd + 2054;

  const float wpa = Wp[col*131 + 0], wpb = Wp[col*131 + 1], wpc = Wp[col*131 + 2];
  float bdv[4];
  #pragma unroll
  for (int g = 0; g < 4; ++g) bdv[g] = bdg[g*128 + col];
  float hwv[6], hbv[6], hcv[6];
  #pragma unroll
  for (int o = 0; o < 6; ++o){
    hwv[o] = hwp[o*128 + col];
    hbv[o] = hbp[o];
    hcv[o] = hcp[o];
  }

  if (tid < 192){
    int r = tid / 3, o = tid - r*3;
    u.prevb[r][o] = x[(size_t)(row0 + r)*90 + 14*6 + o];
  }
  __syncthreads();   // also separates u2 role switch xs -> obuf

  int hcur = 1, hnew = 0;          // h1 buffer / target; hP[2] = dec_in
  #pragma unroll 1
  for (int s = 0; s < 10; ++s){
    unsigned short* bdin = &hP[2][0];
    const unsigned short* bh = &hP[hcur][0];
    unsigned short* bhn = &hP[hnew][0];

    // ph1: dec_in = relu(dbase + prev @ Wp3^T) -> hP[2]
    const float dbs = dbase[s*128 + col];
    #pragma unroll
    for (int m = 0; m < 4; ++m)
      #pragma unroll
      for (int r = 0; r < 4; ++r){
        const int row = m*16 + lgrp*4 + r;
        f32x4 pv = *(const f32x4*)&u.prevb[row][0];
        float v = dbs + pv[0]*wpa + pv[1]*wpb + pv[2]*wpc;
        bdin[sidx(row, col)] = f2bf(v > 0.f ? v : 0.f);
      }
    BAR();

    // ph2: LSTM cell (kt-outer) + fused LN/head partials
    {
      f32x4 acc[4][4];
      #pragma unroll
      for (int m = 0; m < 4; ++m)
        #pragma unroll
        for (int g = 0; g < 4; ++g)
          acc[m][g] = (f32x4){bdv[g], bdv[g], bdv[g], bdv[g]};
      #pragma unroll
      for (int kt = 0; kt < 8; ++kt){
        short8 am[4];
        #pragma unroll
        for (int m = 0; m < 4; ++m){
          if (kt < 4)
            am[m] = *(const short8*)&bdin[sidx(m*16 + lidx, kt*32 + lgrp*8)];
          else
            am[m] = *(const short8*)&bh[sidx(m*16 + lidx, (kt-4)*32 + lgrp*8)];
        }
        #pragma unroll
        for (int g = 0; g < 4; ++g){
          short8 wv = *(const short8*)&pw2[(g*8 + kt)*512];
          #pragma unroll
          for (int m = 0; m < 4; ++m)
            acc[m][g] = __builtin_amdgcn_mfma_f32_16x16x32_bf16(am[m], wv, acc[m][g], 0, 0, 0);
        }
      }
      #pragma unroll
      for (int m = 0; m < 4; ++m)
        #pragma unroll
        for (int r = 0; r < 4; ++r){
          float iv = sigf(acc[m][0][r]);
          float fv = sigf(acc[m][1][r]);
          float gv = tanhf_(acc[m][2][r]);
          float ov = sigf(acc[m][3][r]);
          float c = fv*c1[m][r] + iv*gv;
          c1[m][r] = c;
          float h = ov*tanhf_(c);
          const int row = m*16 + lgrp*4 + r;
          bhn[sidx(row, col)] = f2bf(h);
          float vals[8];
          vals[0] = h; vals[1] = h*h;
          #pragma unroll
          for (int o = 0; o < 6; ++o) vals[2+o] = h*hwv[o];
          #pragma unroll
          for (int d = 1; d < 16; d <<= 1)
            #pragma unroll
            for (int k = 0; k < 8; ++k)
              vals[k] += __shfl_xor(vals[k], d);
          if (lidx == 0){
            *(f32x4*)&u.sred[w][row][0] = (f32x4){vals[0], vals[1], vals[2], vals[3]};
            *(f32x4*)&u.sred[w][row][4] = (f32x4){vals[4], vals[5], vals[6], vals[7]};
          }
        }
    }
    BAR();

    // ph3: per-row finalize (stats + both heads), one thread per row
    if (tid < 64){
      float s1 = 0.f, s2 = 0.f;
      float A[6] = {0.f, 0.f, 0.f, 0.f, 0.f, 0.f};
      #pragma unroll
      for (int ww = 0; ww < 8; ++ww){
        f32x4 v0 = *(const f32x4*)&u.sred[ww][tid][0];
        f32x4 v1 = *(const f32x4*)&u.sred[ww][tid][4];
        s1 += v0[0]; s2 += v0[1];
        A[0] += v0[2]; A[1] += v0[3];
        A[2] += v1[0]; A[3] += v1[1]; A[4] += v1[2]; A[5] += v1[3];
      }
      float mu = s1 * (1.f/128.f);
      float var = s2 * (1.f/128.f) - mu*mu;
      float rs = __builtin_amdgcn_rsqf(var + 1e-5f);
      #pragma unroll
      for (int o = 0; o < 3; ++o){
        float v = rs*(A[o] - mu*hbv[o]) + hcv[o];
        u2.o.om[tid][s*3 + o] = v;
        u.prevb[tid][o] = v;
      }
      #pragma unroll
      for (int o = 3; o < 6; ++o){
        float v = rs*(A[o] - mu*hbv[o]) + hcv[o];
        u2.o.os[tid][s*3 + (o-3)] = fminf(fmaxf(v, -6.f), 3.f);
      }
    }
    BAR();
    int tswap = hcur; hcur = hnew; hnew = tswap;
  }

  // ---- single coalesced output flush ----
  for (int i = tid; i < 1920; i += 512){
    int r = i / 30, cx = i - r*30;
    out[(size_t)(row0 + r)*30 + cx] = u2.o.om[r][cx];
    out[(size_t)65536*30 + (size_t)(row0 + r)*30 + cx] = u2.o.os[r][cx];
  }
}

extern "C" void kernel_launch(void* const* d_in, const int* in_sizes, int n_in,
                              void* d_out, int out_size, void* d_ws, size_t ws_size,
                              hipStream_t stream)
{
  const float* x    = (const float*)d_in[0];
  const float* Wih0 = (const float*)d_in[1];
  const float* Whh0 = (const float*)d_in[2];
  const float* b0   = (const float*)d_in[3];
  const float* Wih1 = (const float*)d_in[4];
  const float* Whh1 = (const float*)d_in[5];
  const float* b1   = (const float*)d_in[6];
  const float* Wihd = (const float*)d_in[7];
  const float* Whhd = (const float*)d_in[8];
  const float* bd   = (const float*)d_in[9];
  const float* emb  = (const float*)d_in[10];
  const float* Wp   = (const float*)d_in[11];
  const float* bp   = (const float*)d_in[12];
  const float* Wm   = (const float*)d_in[13];
  const float* bm   = (const float*)d_in[14];
  const float* Ws   = (const float*)d_in[15];
  const float* bs   = (const float*)d_in[16];
  const float* lng  = (const float*)d_in[17];
  const float* lnb  = (const float*)d_in[18];

  unsigned short* pkw = (unsigned short*)d_ws;
  float* dd = (float*)((char*)d_ws + DD_OFF);

  pack_w<<<(PK_TOTAL + 255)/256, 256, 0, stream>>>(Wih0, Whh0, Wih1, Whh1,
                                                   Wihd, Whhd, Wm, Ws, pkw);
  prep_dec<<<17, 128, 0, stream>>>(emb, Wp, bp, Wm, Ws, bm, bs, lng, lnb, dd);
  traj_main<<<1024, 512, 0, stream>>>(x, pkw, dd, b0, b1, bd, Wp, (float*)d_out);
}